// Round 1
// baseline (1333.250 us; speedup 1.0000x reference)
//
#include <hip/hip_runtime.h>
#include <cmath>

typedef float f32x4 __attribute__((ext_vector_type(4)));
typedef short short8 __attribute__((ext_vector_type(8)));

#define N_POINTS 524288
#define TMASK 0x7FFFFu   // T_MAX-1, hashed levels all have size 2^19

struct HashCfg { int res[16]; int off[16]; unsigned hashed_mask; };

// ---- ws layout (bytes) ----
#define S0_OFF   0        // 256 f32 scale (g/||v||) layer0
#define S1_OFF   1024
#define S2_OFF   2048     // 257 f32
#define W2L_OFF  3328     // 256 f32: normalized last row of v2
#define B0_OFF   4608     // 16nt*3kt*64l*8j bf16 = 49152 B
#define B1_OFF   (B0_OFF + 49152)
#define B2_OFF   (B1_OFF + 131072)
// total = B2_OFF + 131072 = ~316 KB

__device__ inline unsigned short f2bf(float f){
  unsigned u = __float_as_uint(f);
  u = (u + 0x7FFFu + ((u >> 16) & 1u)) >> 16;
  return (unsigned short)u;
}
__device__ inline float bf2f(unsigned short h){
  return __uint_as_float(((unsigned)h) << 16);
}
__device__ inline float softplus100(float x){
  float y = 100.f * x;
  return 0.01f * (fmaxf(y, 0.f) + log1pf(expf(-fabsf(y))));
}

// ---- precompute 1: weight-norm row scales ----
__global__ void scale_kernel(const float* __restrict__ v0, const float* __restrict__ g0,
                             const float* __restrict__ v1, const float* __restrict__ g1,
                             const float* __restrict__ v2, const float* __restrict__ g2,
                             char* __restrict__ ws){
  int r = blockIdx.x * 256 + threadIdx.x;
  if (r < 256){
    float s = 0.f;
    for (int k = 0; k < 71; k++){ float t = v0[r*71+k]; s += t*t; }
    ((float*)(ws + S0_OFF))[r] = g0[r] / sqrtf(s);
  } else if (r < 512){
    int o = r - 256; float s = 0.f;
    for (int k = 0; k < 256; k++){ float t = v1[o*256+k]; s += t*t; }
    ((float*)(ws + S1_OFF))[o] = g1[o] / sqrtf(s);
  } else if (r < 769){
    int o = r - 512; float s = 0.f;
    for (int k = 0; k < 256; k++){ float t = v2[o*256+k]; s += t*t; }
    ((float*)(ws + S2_OFF))[o] = g2[o] / sqrtf(s);
  }
}

// ---- precompute 2: pack normalized weights into MFMA B-fragment order (bf16) ----
// element (nt,kt,l,j): k = kt*32 + (l>>4)*8 + j ; col = nt*16 + (l&15); value = Wn[col][k]
__global__ void pack_kernel(const float* __restrict__ v0, const float* __restrict__ v1,
                            const float* __restrict__ v2, char* __restrict__ ws){
  int i = blockIdx.x * 256 + threadIdx.x;
  const float* s0 = (const float*)(ws + S0_OFF);
  const float* s1 = (const float*)(ws + S1_OFF);
  const float* s2 = (const float*)(ws + S2_OFF);
  if (i < 24576){                  // B0: 16 nt * 3 kt * 512
    int j = i & 7, l = (i >> 3) & 63, q = i >> 9;
    int kt = q % 3, nt = q / 3;
    int k = kt*32 + (l >> 4)*8 + j, col = nt*16 + (l & 15);
    float v = (k < 71) ? v0[col*71 + k] * s0[col] : 0.f;
    ((unsigned short*)(ws + B0_OFF))[i] = f2bf(v);
  } else if (i < 90112){           // B1: 16 nt * 8 kt * 512
    int e = i - 24576;
    int j = e & 7, l = (e >> 3) & 63, q = e >> 9;
    int kt = q & 7, nt = q >> 3;
    int k = kt*32 + (l >> 4)*8 + j, col = nt*16 + (l & 15);
    ((unsigned short*)(ws + B1_OFF))[e] = f2bf(v1[col*256 + k] * s1[col]);
  } else if (i < 155648){          // B2 (first 256 out rows)
    int e = i - 90112;
    int j = e & 7, l = (e >> 3) & 63, q = e >> 9;
    int kt = q & 7, nt = q >> 3;
    int k = kt*32 + (l >> 4)*8 + j, col = nt*16 + (l & 15);
    ((unsigned short*)(ws + B2_OFF))[e] = f2bf(v2[col*256 + k] * s2[col]);
  } else if (i < 155904){          // w2 last row, fp32
    int k = i - 155648;
    ((float*)(ws + W2L_OFF))[k] = v2[256*256 + k] * s2[256];
  }
}

// ---- fused main kernel: 64 points per block, 4 waves ----
__global__ __launch_bounds__(256, 2) void nerf_fused(
    const float* __restrict__ xin, const float* __restrict__ table,
    const char* __restrict__ ws,
    const float* __restrict__ b0, const float* __restrict__ b1, const float* __restrict__ b2,
    float* __restrict__ out, HashCfg cfg)
{
  __shared__ unsigned short bufA[64 * 128];   // h0 bf16 (K padded 71->96), stride 128
  __shared__ unsigned short bufB[64 * 256];   // h1 then h2, stride 256

  const int tid = threadIdx.x;
  const int p   = tid & 63;        // local point
  const int grp = tid >> 6;        // wave id
  const int gp  = blockIdx.x * 64 + p;

  const float x0 = xin[gp*3], x1 = xin[gp*3+1], x2 = xin[gp*3+2];

  auto stA = [&](int row, int col, float v){
    bufA[row*128 + (col ^ ((row & 7) << 3))] = f2bf(v);
  };
  auto stB = [&](int row, int col, float v){
    bufB[row*256 + (col ^ ((row & 7) << 3))] = f2bf(v);
  };

  // ---------- phase 1: features ----------
  if (grp == 0){
    stA(p, 0, x0); stA(p, 1, x1); stA(p, 2, x2);
    float xv[3] = {x0, x1, x2};
    #pragma unroll
    for (int f = 0; f < 6; f++){
      float fr = (float)(1 << f);
      #pragma unroll
      for (int d = 0; d < 3; d++){
        float a = xv[d] * fr;
        stA(p, 3 + f*6 + d,     sinf(a));
        stA(p, 3 + f*6 + 3 + d, cosf(a));
      }
    }
    for (int c = 71; c < 96; c++) stA(p, c, 0.f);   // zero K-pad
  }
  // hash levels: 4 per thread-group
  for (int ii = 0; ii < 4; ii++){
    int l = grp*4 + ii;
    int res = cfg.res[l];
    float scl = (float)(res - 1);
    float px = x0*scl, py = x1*scl, pz = x2*scl;
    float fx = floorf(px), fy = floorf(py), fz = floorf(pz);
    float wx = px - fx, wy = py - fy, wz = pz - fz;
    unsigned cx0 = (unsigned)fx, cy0 = (unsigned)fy, cz0 = (unsigned)fz;
    unsigned r1 = (unsigned)(res + 1);
    bool hl = (cfg.hashed_mask >> l) & 1;
    unsigned base = (unsigned)cfg.off[l];
    float f0 = 0.f, f1 = 0.f;
    #pragma unroll
    for (int c = 0; c < 8; c++){
      unsigned bx = (c >> 2) & 1, by = (c >> 1) & 1, bz = c & 1;
      unsigned cx = cx0 + bx, cy = cy0 + by, cz = cz0 + bz;
      unsigned idx = hl ? ((cx ^ (cy * 2654435761u) ^ (cz * 805459861u)) & TMASK)
                        : (cx + cy * r1 + cz * r1 * r1);
      const float2 fv = *(const float2*)(table + (size_t)(base + idx) * 2u);
      float w = (bx ? wx : 1.f - wx) * (by ? wy : 1.f - wy) * (bz ? wz : 1.f - wz);
      f0 += w * fv.x; f1 += w * fv.y;
    }
    stA(p, 39 + 2*l, f0);
    stA(p, 40 + 2*l, f1);
  }
  __syncthreads();

  // ---------- MFMA phases ----------
  const int l  = tid & 63;
  const int lr = l & 15;    // A-row / B-col / C-col within tile
  const int lh = l >> 4;    // k-group; C-row = lh*4 + j
  const int wv = grp;       // wave owns output cols [wv*64, wv*64+64)
  const short8* B0p = (const short8*)(ws + B0_OFF);
  const short8* B1p = (const short8*)(ws + B1_OFF);
  const short8* B2p = (const short8*)(ws + B2_OFF);

  auto ldA = [&](int row, int kb) -> short8 {
    return *(const short8*)&bufA[row*128 + (kb ^ ((row & 7) << 3))];
  };
  auto ldB = [&](int row, int kb) -> short8 {
    return *(const short8*)&bufB[row*256 + (kb ^ ((row & 7) << 3))];
  };

  { // ----- layer 0: [64 x 96] @ [96 x 256] -----
    f32x4 acc[4][4];
    #pragma unroll
    for (int a = 0; a < 4; a++)
      #pragma unroll
      for (int b = 0; b < 4; b++) acc[a][b] = (f32x4){0.f,0.f,0.f,0.f};
    for (int kt = 0; kt < 3; kt++){
      short8 af[4];
      #pragma unroll
      for (int mt = 0; mt < 4; mt++) af[mt] = ldA(mt*16 + lr, kt*32 + lh*8);
      #pragma unroll
      for (int nt = 0; nt < 4; nt++){
        short8 bf = B0p[((wv*4 + nt)*3 + kt)*64 + l];
        #pragma unroll
        for (int mt = 0; mt < 4; mt++)
          acc[mt][nt] = __builtin_amdgcn_mfma_f32_16x16x32_bf16(af[mt], bf, acc[mt][nt], 0, 0, 0);
      }
    }
    #pragma unroll
    for (int mt = 0; mt < 4; mt++)
      #pragma unroll
      for (int nt = 0; nt < 4; nt++){
        int c = wv*64 + nt*16 + lr;
        float bb = b0[c];
        #pragma unroll
        for (int j = 0; j < 4; j++)
          stB(mt*16 + lh*4 + j, c, softplus100(acc[mt][nt][j] + bb));
      }
  }
  __syncthreads();

  { // ----- layer 1: [64 x 256] @ [256 x 256] -----
    f32x4 acc[4][4];
    #pragma unroll
    for (int a = 0; a < 4; a++)
      #pragma unroll
      for (int b = 0; b < 4; b++) acc[a][b] = (f32x4){0.f,0.f,0.f,0.f};
    for (int kt = 0; kt < 8; kt++){
      short8 af[4];
      #pragma unroll
      for (int mt = 0; mt < 4; mt++) af[mt] = ldB(mt*16 + lr, kt*32 + lh*8);
      #pragma unroll
      for (int nt = 0; nt < 4; nt++){
        short8 bf = B1p[((wv*4 + nt)*8 + kt)*64 + l];
        #pragma unroll
        for (int mt = 0; mt < 4; mt++)
          acc[mt][nt] = __builtin_amdgcn_mfma_f32_16x16x32_bf16(af[mt], bf, acc[mt][nt], 0, 0, 0);
      }
    }
    __syncthreads();   // all h1 reads complete before overwriting bufB with h2
    #pragma unroll
    for (int mt = 0; mt < 4; mt++)
      #pragma unroll
      for (int nt = 0; nt < 4; nt++){
        int c = wv*64 + nt*16 + lr;
        float bb = b1[c];
        #pragma unroll
        for (int j = 0; j < 4; j++)
          stB(mt*16 + lh*4 + j, c, softplus100(acc[mt][nt][j] + bb));
      }
  }
  __syncthreads();

  { // ----- layer 2: [64 x 256] @ [256 x 256] (+ col 256 via VALU) -----
    f32x4 acc[4][4];
    #pragma unroll
    for (int a = 0; a < 4; a++)
      #pragma unroll
      for (int b = 0; b < 4; b++) acc[a][b] = (f32x4){0.f,0.f,0.f,0.f};
    for (int kt = 0; kt < 8; kt++){
      short8 af[4];
      #pragma unroll
      for (int mt = 0; mt < 4; mt++) af[mt] = ldB(mt*16 + lr, kt*32 + lh*8);
      #pragma unroll
      for (int nt = 0; nt < 4; nt++){
        short8 bf = B2p[((wv*4 + nt)*8 + kt)*64 + l];
        #pragma unroll
        for (int mt = 0; mt < 4; mt++)
          acc[mt][nt] = __builtin_amdgcn_mfma_f32_16x16x32_bf16(af[mt], bf, acc[mt][nt], 0, 0, 0);
      }
    }
    #pragma unroll
    for (int mt = 0; mt < 4; mt++)
      #pragma unroll
      for (int nt = 0; nt < 4; nt++){
        int c = wv*64 + nt*16 + lr;
        float bb = b2[c];
        #pragma unroll
        for (int j = 0; j < 4; j++){
          int r = mt*16 + lh*4 + j;
          out[(size_t)(blockIdx.x*64 + r)*257 + c] = acc[mt][nt][j] + bb;
        }
      }
  }
  // last output column (index 256): dot(h2, w2last) + b2[256]
  if (tid < 64){
    const float* w2l = (const float*)(ws + W2L_OFF);
    float dot = b2[256];
    for (int k8 = 0; k8 < 32; k8++){
      int elem = (k8*8) ^ ((p & 7) << 3);
      short8 hv = *(const short8*)&bufB[p*256 + elem];
      #pragma unroll
      for (int j = 0; j < 8; j++)
        dot += bf2f((unsigned short)hv[j]) * w2l[k8*8 + j];
    }
    out[(size_t)gp * 257 + 256] = dot;
  }
}

// ---- host: replicate reference's double-precision level config exactly ----
static HashCfg make_cfg(){
  HashCfg c;
  double pls = exp2(log2(2048.0 / 16.0) / 15.0);
  long long off = 0;
  unsigned mask = 0;
  for (int l = 0; l < 16; l++){
    int r = (int)ceil(16.0 * pow(pls, (double)l));
    c.res[l] = r;
    c.off[l] = (int)off;
    double n3 = (double)(r + 1) * (double)(r + 1) * (double)(r + 1);
    long long size;
    if (n3 > 524288.0){ mask |= (1u << l); }
    size = (long long)(ceil(n3 / 8.0) * 8.0);
    if (size > 524288) size = 524288;
    off += size;
  }
  c.hashed_mask = mask;
  return c;
}

extern "C" void kernel_launch(void* const* d_in, const int* in_sizes, int n_in,
                              void* d_out, int out_size, void* d_ws, size_t ws_size,
                              hipStream_t stream) {
  const float* x     = (const float*)d_in[0];
  const float* table = (const float*)d_in[1];
  const float* v0 = (const float*)d_in[2];
  const float* g0 = (const float*)d_in[3];
  const float* b0 = (const float*)d_in[4];
  const float* v1 = (const float*)d_in[5];
  const float* g1 = (const float*)d_in[6];
  const float* b1 = (const float*)d_in[7];
  const float* v2 = (const float*)d_in[8];
  const float* g2 = (const float*)d_in[9];
  const float* b2 = (const float*)d_in[10];
  float* out = (float*)d_out;
  char* ws = (char*)d_ws;

  HashCfg cfg = make_cfg();

  hipLaunchKernelGGL(scale_kernel, dim3(4), dim3(256), 0, stream, v0, g0, v1, g1, v2, g2, ws);
  hipLaunchKernelGGL(pack_kernel, dim3(609), dim3(256), 0, stream, v0, v1, v2, ws);
  hipLaunchKernelGGL(nerf_fused, dim3(N_POINTS / 64), dim3(256), 0, stream,
                     x, table, ws, b0, b1, b2, out, cfg);
}

// Round 2
// 1159.207 us; speedup vs baseline: 1.1501x; 1.1501x over previous
//
#include <hip/hip_runtime.h>
#include <cmath>

typedef float f32x4 __attribute__((ext_vector_type(4)));
typedef short short8 __attribute__((ext_vector_type(8)));

#define N_POINTS 524288
#define TMASK 0x7FFFFu   // T_MAX-1, hashed levels all have size 2^19

struct HashCfg { int res[16]; int off[16]; unsigned hashed_mask; };

// ---- ws layout (bytes) ----
#define S0_OFF   0        // 256 f32 scale (g/||v||) layer0
#define S1_OFF   1024
#define S2_OFF   2048     // 257 f32
#define W2L_OFF  3328     // 256 f32: normalized last row of v2
#define B0_OFF   4608     // 16nt*3kt*64l*8j bf16 = 49152 B
#define B1_OFF   (B0_OFF + 49152)
#define B2_OFF   (B1_OFF + 131072)
#define PACKA_OFF (B2_OFF + 131072)            // = 315904, 512-aligned
#define PACKA_BYTES ((size_t)8192 * 12288)     // 8192 blocks * 768 short8 * 16B = 100663296
#define WS_NEED (PACKA_OFF + PACKA_BYTES)

__device__ inline unsigned short f2bf(float f){
  unsigned u = __float_as_uint(f);
  u = (u + 0x7FFFu + ((u >> 16) & 1u)) >> 16;
  return (unsigned short)u;
}
__device__ inline float bf2f(unsigned short h){
  return __uint_as_float(((unsigned)h) << 16);
}
// precise version (fallback kernel)
__device__ inline float softplus100(float x){
  float y = 100.f * x;
  return 0.01f * (fmaxf(y, 0.f) + log1pf(expf(-fabsf(y))));
}
// fast version: |error| < 1e-7 absolute, far below bf16 storage rounding
__device__ inline float softplus100_fast(float x){
  float y = 100.f * x;
  return 0.01f * (fmaxf(y, 0.f) + __logf(1.f + __expf(-fabsf(y))));
}

// ---- precompute 1: weight-norm row scales ----
__global__ void scale_kernel(const float* __restrict__ v0, const float* __restrict__ g0,
                             const float* __restrict__ v1, const float* __restrict__ g1,
                             const float* __restrict__ v2, const float* __restrict__ g2,
                             char* __restrict__ ws){
  int r = blockIdx.x * 256 + threadIdx.x;
  if (r < 256){
    float s = 0.f;
    for (int k = 0; k < 71; k++){ float t = v0[r*71+k]; s += t*t; }
    ((float*)(ws + S0_OFF))[r] = g0[r] / sqrtf(s);
  } else if (r < 512){
    int o = r - 256; float s = 0.f;
    for (int k = 0; k < 256; k++){ float t = v1[o*256+k]; s += t*t; }
    ((float*)(ws + S1_OFF))[o] = g1[o] / sqrtf(s);
  } else if (r < 769){
    int o = r - 512; float s = 0.f;
    for (int k = 0; k < 256; k++){ float t = v2[o*256+k]; s += t*t; }
    ((float*)(ws + S2_OFF))[o] = g2[o] / sqrtf(s);
  }
}

// ---- precompute 2: pack normalized weights into MFMA B-fragment order (bf16) ----
// element (nt,kt,l,j): k = kt*32 + (l>>4)*8 + j ; col = nt*16 + (l&15); value = Wn[col][k]
__global__ void pack_kernel(const float* __restrict__ v0, const float* __restrict__ v1,
                            const float* __restrict__ v2, char* __restrict__ ws){
  int i = blockIdx.x * 256 + threadIdx.x;
  const float* s0 = (const float*)(ws + S0_OFF);
  const float* s1 = (const float*)(ws + S1_OFF);
  const float* s2 = (const float*)(ws + S2_OFF);
  if (i < 24576){                  // B0: 16 nt * 3 kt * 512
    int j = i & 7, l = (i >> 3) & 63, q = i >> 9;
    int kt = q % 3, nt = q / 3;
    int k = kt*32 + (l >> 4)*8 + j, col = nt*16 + (l & 15);
    float v = (k < 71) ? v0[col*71 + k] * s0[col] : 0.f;
    ((unsigned short*)(ws + B0_OFF))[i] = f2bf(v);
  } else if (i < 90112){           // B1: 16 nt * 8 kt * 512
    int e = i - 24576;
    int j = e & 7, l = (e >> 3) & 63, q = e >> 9;
    int kt = q & 7, nt = q >> 3;
    int k = kt*32 + (l >> 4)*8 + j, col = nt*16 + (l & 15);
    ((unsigned short*)(ws + B1_OFF))[e] = f2bf(v1[col*256 + k] * s1[col]);
  } else if (i < 155648){          // B2 (first 256 out rows)
    int e = i - 90112;
    int j = e & 7, l = (e >> 3) & 63, q = e >> 9;
    int kt = q & 7, nt = q >> 3;
    int k = kt*32 + (l >> 4)*8 + j, col = nt*16 + (l & 15);
    ((unsigned short*)(ws + B2_OFF))[e] = f2bf(v2[col*256 + k] * s2[col]);
  } else if (i < 155904){          // w2 last row, fp32
    int k = i - 155648;
    ((float*)(ws + W2L_OFF))[k] = v2[256*256 + k] * s2[256];
  }
}

// ============================================================================
// Split path kernel 1: encode. 64 points/block, 256 threads.
// Writes bf16 features pre-packed in MFMA A-fragment order:
//   packA[blk][kt][mt][l] (short8) = A[mt*16+(l&15)][kt*32+(l>>4)*8 .. +8]
// ============================================================================
__global__ __launch_bounds__(256, 4) void enc_kernel(
    const float* __restrict__ xin, const float* __restrict__ table,
    char* __restrict__ ws, HashCfg cfg)
{
  __shared__ unsigned short fl[64][104];   // row-major features, padded stride

  const int tid = threadIdx.x;
  const int p   = tid & 63;
  const int grp = tid >> 6;
  const int gp  = blockIdx.x * 64 + p;

  const float x0 = xin[gp*3], x1 = xin[gp*3+1], x2 = xin[gp*3+2];
  float xv[3] = {x0, x1, x2};

  if (grp < 3){
    // each of grp 0..2 handles 2 freqs
    #pragma unroll
    for (int fi = 0; fi < 2; fi++){
      int f = grp*2 + fi;
      float fr = (float)(1 << f);
      #pragma unroll
      for (int d = 0; d < 3; d++){
        float a = xv[d] * fr;
        fl[p][3 + f*6 + d]     = f2bf(__sinf(a));
        fl[p][3 + f*6 + 3 + d] = f2bf(__cosf(a));
      }
    }
  } else {
    fl[p][0] = f2bf(x0); fl[p][1] = f2bf(x1); fl[p][2] = f2bf(x2);
    #pragma unroll
    for (int c = 71; c < 96; c++) fl[p][c] = 0;   // K-pad
  }

  // hash levels: 4 per grp
  for (int ii = 0; ii < 4; ii++){
    int lev = grp*4 + ii;
    int res = cfg.res[lev];
    float scl = (float)(res - 1);
    float px = x0*scl, py = x1*scl, pz = x2*scl;
    float fx = floorf(px), fy = floorf(py), fz = floorf(pz);
    float wx = px - fx, wy = py - fy, wz = pz - fz;
    unsigned cx0 = (unsigned)fx, cy0 = (unsigned)fy, cz0 = (unsigned)fz;
    unsigned r1 = (unsigned)(res + 1);
    bool hl = (cfg.hashed_mask >> lev) & 1;
    unsigned base = (unsigned)cfg.off[lev];
    float f0 = 0.f, f1 = 0.f;
    #pragma unroll
    for (int c = 0; c < 8; c++){
      unsigned bx = (c >> 2) & 1, by = (c >> 1) & 1, bz = c & 1;
      unsigned cx = cx0 + bx, cy = cy0 + by, cz = cz0 + bz;
      unsigned idx = hl ? ((cx ^ (cy * 2654435761u) ^ (cz * 805459861u)) & TMASK)
                        : (cx + cy * r1 + cz * r1 * r1);
      const float2 fv = *(const float2*)(table + (size_t)(base + idx) * 2u);
      float w = (bx ? wx : 1.f - wx) * (by ? wy : 1.f - wy) * (bz ? wz : 1.f - wz);
      f0 += w * fv.x; f1 += w * fv.y;
    }
    fl[p][39 + 2*lev] = f2bf(f0);
    fl[p][40 + 2*lev] = f2bf(f1);
  }
  __syncthreads();

  // pack to global: 768 short8 per block, 3 per thread, coalesced stores
  short8* pA = (short8*)(ws + PACKA_OFF) + (size_t)blockIdx.x * 768;
  #pragma unroll
  for (int i = 0; i < 3; i++){
    int e = tid + 256*i;
    int lq = e & 63, q = e >> 6;
    int mt = q & 3, kt = q >> 2;
    int row = mt*16 + (lq & 15);
    int kb  = kt*32 + (lq >> 4)*8;
    pA[e] = *(const short8*)&fl[row][kb];
  }
}

// ============================================================================
// Split path kernel 2: MLP. 64 rows/block, 4 waves, each wave owns 64 cols.
// A(layer0) register-direct from packed global; hA/hB recycled in one 32KB
// swizzled LDS buffer.
// ============================================================================
__global__ __launch_bounds__(256, 4) void mlp_kernel(
    const char* __restrict__ ws,
    const float* __restrict__ b0, const float* __restrict__ b1, const float* __restrict__ b2,
    float* __restrict__ out)
{
  __shared__ unsigned short buf[64 * 256];  // swizzled: elem(row,col) at col^((row&7)<<3)
  __shared__ float colsc[4][64];

  const int tid = threadIdx.x;
  const int l  = tid & 63;
  const int wv = tid >> 6;
  const int lr = l & 15;
  const int lh = l >> 4;

  const short8* Ap  = (const short8*)(ws + PACKA_OFF) + (size_t)blockIdx.x * 768;
  const short8* B0p = (const short8*)(ws + B0_OFF);
  const short8* B1p = (const short8*)(ws + B1_OFF);
  const short8* B2p = (const short8*)(ws + B2_OFF);

  auto stB = [&](int row, int col, float v){
    buf[row*256 + (col ^ ((row & 7) << 3))] = f2bf(v);
  };
  auto ldB = [&](int row, int kb) -> short8 {
    return *(const short8*)&buf[row*256 + (kb ^ ((row & 7) << 3))];
  };

  { // ----- layer 0: A from global (fragment-packed) -----
    f32x4 acc[4][4];
    #pragma unroll
    for (int a = 0; a < 4; a++)
      #pragma unroll
      for (int b = 0; b < 4; b++) acc[a][b] = (f32x4){0.f,0.f,0.f,0.f};
    #pragma unroll
    for (int kt = 0; kt < 3; kt++){
      short8 af[4];
      #pragma unroll
      for (int mt = 0; mt < 4; mt++) af[mt] = Ap[(kt*4 + mt)*64 + l];
      #pragma unroll
      for (int nt = 0; nt < 4; nt++){
        short8 bf = B0p[((wv*4 + nt)*3 + kt)*64 + l];
        #pragma unroll
        for (int mt = 0; mt < 4; mt++)
          acc[mt][nt] = __builtin_amdgcn_mfma_f32_16x16x32_bf16(af[mt], bf, acc[mt][nt], 0, 0, 0);
      }
    }
    float bb[4];
    #pragma unroll
    for (int nt = 0; nt < 4; nt++) bb[nt] = b0[wv*64 + nt*16 + lr];
    #pragma unroll
    for (int mt = 0; mt < 4; mt++)
      #pragma unroll
      for (int nt = 0; nt < 4; nt++){
        int c = wv*64 + nt*16 + lr;
        #pragma unroll
        for (int j = 0; j < 4; j++)
          stB(mt*16 + lh*4 + j, c, softplus100_fast(acc[mt][nt][j] + bb[nt]));
      }
  }
  __syncthreads();

  { // ----- layer 1 -----
    f32x4 acc[4][4];
    #pragma unroll
    for (int a = 0; a < 4; a++)
      #pragma unroll
      for (int b = 0; b < 4; b++) acc[a][b] = (f32x4){0.f,0.f,0.f,0.f};
    #pragma unroll
    for (int kt = 0; kt < 8; kt++){
      short8 af[4];
      #pragma unroll
      for (int mt = 0; mt < 4; mt++) af[mt] = ldB(mt*16 + lr, kt*32 + lh*8);
      #pragma unroll
      for (int nt = 0; nt < 4; nt++){
        short8 bf = B1p[((wv*4 + nt)*8 + kt)*64 + l];
        #pragma unroll
        for (int mt = 0; mt < 4; mt++)
          acc[mt][nt] = __builtin_amdgcn_mfma_f32_16x16x32_bf16(af[mt], bf, acc[mt][nt], 0, 0, 0);
      }
    }
    __syncthreads();   // all hA reads complete before overwriting buf with hB
    float bb[4];
    #pragma unroll
    for (int nt = 0; nt < 4; nt++) bb[nt] = b1[wv*64 + nt*16 + lr];
    #pragma unroll
    for (int mt = 0; mt < 4; mt++)
      #pragma unroll
      for (int nt = 0; nt < 4; nt++){
        int c = wv*64 + nt*16 + lr;
        #pragma unroll
        for (int j = 0; j < 4; j++)
          stB(mt*16 + lh*4 + j, c, softplus100_fast(acc[mt][nt][j] + bb[nt]));
      }
  }
  __syncthreads();  // hB visible to all

  // last-col partials: thread (wv,l) handles row l, cols [wv*64, wv*64+64)
  {
    const float* w2l = (const float*)(ws + W2L_OFF);
    float s = 0.f;
    #pragma unroll
    for (int q = 0; q < 8; q++){
      short8 h = ldB(l, wv*64 + q*8);
      #pragma unroll
      for (int j = 0; j < 8; j++)
        s += bf2f((unsigned short)h[j]) * w2l[wv*64 + q*8 + j];
    }
    colsc[wv][l] = s;
  }

  { // ----- layer 2 -----
    f32x4 acc[4][4];
    #pragma unroll
    for (int a = 0; a < 4; a++)
      #pragma unroll
      for (int b = 0; b < 4; b++) acc[a][b] = (f32x4){0.f,0.f,0.f,0.f};
    #pragma unroll
    for (int kt = 0; kt < 8; kt++){
      short8 af[4];
      #pragma unroll
      for (int mt = 0; mt < 4; mt++) af[mt] = ldB(mt*16 + lr, kt*32 + lh*8);
      #pragma unroll
      for (int nt = 0; nt < 4; nt++){
        short8 bf = B2p[((wv*4 + nt)*8 + kt)*64 + l];
        #pragma unroll
        for (int mt = 0; mt < 4; mt++)
          acc[mt][nt] = __builtin_amdgcn_mfma_f32_16x16x32_bf16(af[mt], bf, acc[mt][nt], 0, 0, 0);
      }
    }
    __syncthreads();   // colsc partials visible
    float bb[4];
    #pragma unroll
    for (int nt = 0; nt < 4; nt++) bb[nt] = b2[wv*64 + nt*16 + lr];
    #pragma unroll
    for (int mt = 0; mt < 4; mt++)
      #pragma unroll
      for (int nt = 0; nt < 4; nt++){
        int c = wv*64 + nt*16 + lr;
        #pragma unroll
        for (int j = 0; j < 4; j++){
          int r = mt*16 + lh*4 + j;
          out[(size_t)(blockIdx.x*64 + r)*257 + c] = acc[mt][nt][j] + bb[nt];
        }
      }
    if (tid < 64)
      out[(size_t)(blockIdx.x*64 + tid)*257 + 256] =
        colsc[0][tid] + colsc[1][tid] + colsc[2][tid] + colsc[3][tid] + b2[256];
  }
}

// ============================================================================
// Fallback: original fused kernel (used only if ws too small for packed A)
// ============================================================================
__global__ __launch_bounds__(256, 2) void nerf_fused(
    const float* __restrict__ xin, const float* __restrict__ table,
    const char* __restrict__ ws,
    const float* __restrict__ b0, const float* __restrict__ b1, const float* __restrict__ b2,
    float* __restrict__ out, HashCfg cfg)
{
  __shared__ unsigned short bufA[64 * 128];
  __shared__ unsigned short bufB[64 * 256];

  const int tid = threadIdx.x;
  const int p   = tid & 63;
  const int grp = tid >> 6;
  const int gp  = blockIdx.x * 64 + p;

  const float x0 = xin[gp*3], x1 = xin[gp*3+1], x2 = xin[gp*3+2];

  auto stA = [&](int row, int col, float v){
    bufA[row*128 + (col ^ ((row & 7) << 3))] = f2bf(v);
  };
  auto stB = [&](int row, int col, float v){
    bufB[row*256 + (col ^ ((row & 7) << 3))] = f2bf(v);
  };

  if (grp == 0){
    stA(p, 0, x0); stA(p, 1, x1); stA(p, 2, x2);
    float xv[3] = {x0, x1, x2};
    #pragma unroll
    for (int f = 0; f < 6; f++){
      float fr = (float)(1 << f);
      #pragma unroll
      for (int d = 0; d < 3; d++){
        float a = xv[d] * fr;
        stA(p, 3 + f*6 + d,     sinf(a));
        stA(p, 3 + f*6 + 3 + d, cosf(a));
      }
    }
    for (int c = 71; c < 96; c++) stA(p, c, 0.f);
  }
  for (int ii = 0; ii < 4; ii++){
    int lv = grp*4 + ii;
    int res = cfg.res[lv];
    float scl = (float)(res - 1);
    float px = x0*scl, py = x1*scl, pz = x2*scl;
    float fx = floorf(px), fy = floorf(py), fz = floorf(pz);
    float wx = px - fx, wy = py - fy, wz = pz - fz;
    unsigned cx0 = (unsigned)fx, cy0 = (unsigned)fy, cz0 = (unsigned)fz;
    unsigned r1 = (unsigned)(res + 1);
    bool hl = (cfg.hashed_mask >> lv) & 1;
    unsigned base = (unsigned)cfg.off[lv];
    float f0 = 0.f, f1 = 0.f;
    #pragma unroll
    for (int c = 0; c < 8; c++){
      unsigned bx = (c >> 2) & 1, by = (c >> 1) & 1, bz = c & 1;
      unsigned cx = cx0 + bx, cy = cy0 + by, cz = cz0 + bz;
      unsigned idx = hl ? ((cx ^ (cy * 2654435761u) ^ (cz * 805459861u)) & TMASK)
                        : (cx + cy * r1 + cz * r1 * r1);
      const float2 fv = *(const float2*)(table + (size_t)(base + idx) * 2u);
      float w = (bx ? wx : 1.f - wx) * (by ? wy : 1.f - wy) * (bz ? wz : 1.f - wz);
      f0 += w * fv.x; f1 += w * fv.y;
    }
    stA(p, 39 + 2*lv, f0);
    stA(p, 40 + 2*lv, f1);
  }
  __syncthreads();

  const int l  = tid & 63;
  const int lr = l & 15;
  const int lh = l >> 4;
  const int wv = grp;
  const short8* B0p = (const short8*)(ws + B0_OFF);
  const short8* B1p = (const short8*)(ws + B1_OFF);
  const short8* B2p = (const short8*)(ws + B2_OFF);

  auto ldA = [&](int row, int kb) -> short8 {
    return *(const short8*)&bufA[row*128 + (kb ^ ((row & 7) << 3))];
  };
  auto ldB = [&](int row, int kb) -> short8 {
    return *(const short8*)&bufB[row*256 + (kb ^ ((row & 7) << 3))];
  };

  {
    f32x4 acc[4][4];
    #pragma unroll
    for (int a = 0; a < 4; a++)
      #pragma unroll
      for (int b = 0; b < 4; b++) acc[a][b] = (f32x4){0.f,0.f,0.f,0.f};
    for (int kt = 0; kt < 3; kt++){
      short8 af[4];
      #pragma unroll
      for (int mt = 0; mt < 4; mt++) af[mt] = ldA(mt*16 + lr, kt*32 + lh*8);
      #pragma unroll
      for (int nt = 0; nt < 4; nt++){
        short8 bf = B0p[((wv*4 + nt)*3 + kt)*64 + l];
        #pragma unroll
        for (int mt = 0; mt < 4; mt++)
          acc[mt][nt] = __builtin_amdgcn_mfma_f32_16x16x32_bf16(af[mt], bf, acc[mt][nt], 0, 0, 0);
      }
    }
    #pragma unroll
    for (int mt = 0; mt < 4; mt++)
      #pragma unroll
      for (int nt = 0; nt < 4; nt++){
        int c = wv*64 + nt*16 + lr;
        float bbv = b0[c];
        #pragma unroll
        for (int j = 0; j < 4; j++)
          stB(mt*16 + lh*4 + j, c, softplus100(acc[mt][nt][j] + bbv));
      }
  }
  __syncthreads();

  {
    f32x4 acc[4][4];
    #pragma unroll
    for (int a = 0; a < 4; a++)
      #pragma unroll
      for (int b = 0; b < 4; b++) acc[a][b] = (f32x4){0.f,0.f,0.f,0.f};
    for (int kt = 0; kt < 8; kt++){
      short8 af[4];
      #pragma unroll
      for (int mt = 0; mt < 4; mt++) af[mt] = ldB(mt*16 + lr, kt*32 + lh*8);
      #pragma unroll
      for (int nt = 0; nt < 4; nt++){
        short8 bf = B1p[((wv*4 + nt)*8 + kt)*64 + l];
        #pragma unroll
        for (int mt = 0; mt < 4; mt++)
          acc[mt][nt] = __builtin_amdgcn_mfma_f32_16x16x32_bf16(af[mt], bf, acc[mt][nt], 0, 0, 0);
      }
    }
    __syncthreads();
    #pragma unroll
    for (int mt = 0; mt < 4; mt++)
      #pragma unroll
      for (int nt = 0; nt < 4; nt++){
        int c = wv*64 + nt*16 + lr;
        float bbv = b1[c];
        #pragma unroll
        for (int j = 0; j < 4; j++)
          stB(mt*16 + lh*4 + j, c, softplus100(acc[mt][nt][j] + bbv));
      }
  }
  __syncthreads();

  {
    f32x4 acc[4][4];
    #pragma unroll
    for (int a = 0; a < 4; a++)
      #pragma unroll
      for (int b = 0; b < 4; b++) acc[a][b] = (f32x4){0.f,0.f,0.f,0.f};
    for (int kt = 0; kt < 8; kt++){
      short8 af[4];
      #pragma unroll
      for (int mt = 0; mt < 4; mt++) af[mt] = ldB(mt*16 + lr, kt*32 + lh*8);
      #pragma unroll
      for (int nt = 0; nt < 4; nt++){
        short8 bf = B2p[((wv*4 + nt)*8 + kt)*64 + l];
        #pragma unroll
        for (int mt = 0; mt < 4; mt++)
          acc[mt][nt] = __builtin_amdgcn_mfma_f32_16x16x32_bf16(af[mt], bf, acc[mt][nt], 0, 0, 0);
      }
    }
    #pragma unroll
    for (int mt = 0; mt < 4; mt++)
      #pragma unroll
      for (int nt = 0; nt < 4; nt++){
        int c = wv*64 + nt*16 + lr;
        float bbv = b2[c];
        #pragma unroll
        for (int j = 0; j < 4; j++){
          int r = mt*16 + lh*4 + j;
          out[(size_t)(blockIdx.x*64 + r)*257 + c] = acc[mt][nt][j] + bbv;
        }
      }
  }
  if (tid < 64){
    const float* w2l = (const float*)(ws + W2L_OFF);
    float dot = b2[256];
    for (int k8 = 0; k8 < 32; k8++){
      int elem = (k8*8) ^ ((p & 7) << 3);
      short8 hv = *(const short8*)&bufB[p*256 + elem];
      #pragma unroll
      for (int j = 0; j < 8; j++)
        dot += bf2f((unsigned short)hv[j]) * w2l[k8*8 + j];
    }
    out[(size_t)gp * 257 + 256] = dot;
  }
}

// ---- host: replicate reference's double-precision level config exactly ----
static HashCfg make_cfg(){
  HashCfg c;
  double pls = exp2(log2(2048.0 / 16.0) / 15.0);
  long long off = 0;
  unsigned mask = 0;
  for (int l = 0; l < 16; l++){
    int r = (int)ceil(16.0 * pow(pls, (double)l));
    c.res[l] = r;
    c.off[l] = (int)off;
    double n3 = (double)(r + 1) * (double)(r + 1) * (double)(r + 1);
    long long size;
    if (n3 > 524288.0){ mask |= (1u << l); }
    size = (long long)(ceil(n3 / 8.0) * 8.0);
    if (size > 524288) size = 524288;
    off += size;
  }
  c.hashed_mask = mask;
  return c;
}

extern "C" void kernel_launch(void* const* d_in, const int* in_sizes, int n_in,
                              void* d_out, int out_size, void* d_ws, size_t ws_size,
                              hipStream_t stream) {
  const float* x     = (const float*)d_in[0];
  const float* table = (const float*)d_in[1];
  const float* v0 = (const float*)d_in[2];
  const float* g0 = (const float*)d_in[3];
  const float* b0 = (const float*)d_in[4];
  const float* v1 = (const float*)d_in[5];
  const float* g1 = (const float*)d_in[6];
  const float* b1 = (const float*)d_in[7];
  const float* v2 = (const float*)d_in[8];
  const float* g2 = (const float*)d_in[9];
  const float* b2 = (const float*)d_in[10];
  float* out = (float*)d_out;
  char* ws = (char*)d_ws;

  HashCfg cfg = make_cfg();

  hipLaunchKernelGGL(scale_kernel, dim3(4), dim3(256), 0, stream, v0, g0, v1, g1, v2, g2, ws);
  hipLaunchKernelGGL(pack_kernel, dim3(609), dim3(256), 0, stream, v0, v1, v2, ws);

  if (ws_size >= WS_NEED){
    hipLaunchKernelGGL(enc_kernel, dim3(N_POINTS / 64), dim3(256), 0, stream, x, table, ws, cfg);
    hipLaunchKernelGGL(mlp_kernel, dim3(N_POINTS / 64), dim3(256), 0, stream,
                       ws, b0, b1, b2, out);
  } else {
    hipLaunchKernelGGL(nerf_fused, dim3(N_POINTS / 64), dim3(256), 0, stream,
                       x, table, ws, b0, b1, b2, out, cfg);
  }
}

// Round 3
// 1067.024 us; speedup vs baseline: 1.2495x; 1.0864x over previous
//
#include <hip/hip_runtime.h>
#include <cmath>

typedef float f32x4 __attribute__((ext_vector_type(4)));
typedef short short8 __attribute__((ext_vector_type(8)));

#define N_POINTS 524288
#define TMASK 0x7FFFFu   // T_MAX-1, hashed levels all have size 2^19

struct HashCfg { int res[16]; int off[16]; unsigned hashed_mask; int total; };

// ---- ws layout (bytes) ----
#define S0_OFF   0        // 256 f32 scale (g/||v||) layer0
#define S1_OFF   1024
#define S2_OFF   2048     // 257 f32
#define W2L_OFF  3328     // 256 f32: normalized last row of v2
#define B0_OFF   4608     // 16nt*3kt*64l*8j bf16 = 49152 B
#define B1_OFF   (B0_OFF + 49152)
#define B2_OFF   (B1_OFF + 131072)
#define PACKA_OFF (B2_OFF + 131072)            // = 315904, 512-aligned
#define PACKA_BYTES ((size_t)8192 * 12288)     // 8192 blocks * 768 short8 * 16B
#define TBF_OFF   (PACKA_OFF + PACKA_BYTES)    // bf16x2 table copy
#define WS_NEED   (PACKA_OFF + PACKA_BYTES)

__device__ inline unsigned short f2bf(float f){
  unsigned u = __float_as_uint(f);
  u = (u + 0x7FFFu + ((u >> 16) & 1u)) >> 16;
  return (unsigned short)u;
}
__device__ inline float bf2f(unsigned short h){
  return __uint_as_float(((unsigned)h) << 16);
}
__device__ inline float softplus100(float x){
  float y = 100.f * x;
  return 0.01f * (fmaxf(y, 0.f) + log1pf(expf(-fabsf(y))));
}
__device__ inline float softplus100_fast(float x){
  float y = 100.f * x;
  return 0.01f * (fmaxf(y, 0.f) + __logf(1.f + __expf(-fabsf(y))));
}

// ---- precompute 1: weight-norm row scales ----
__global__ void scale_kernel(const float* __restrict__ v0, const float* __restrict__ g0,
                             const float* __restrict__ v1, const float* __restrict__ g1,
                             const float* __restrict__ v2, const float* __restrict__ g2,
                             char* __restrict__ ws){
  int r = blockIdx.x * 256 + threadIdx.x;
  if (r < 256){
    float s = 0.f;
    for (int k = 0; k < 71; k++){ float t = v0[r*71+k]; s += t*t; }
    ((float*)(ws + S0_OFF))[r] = g0[r] / sqrtf(s);
  } else if (r < 512){
    int o = r - 256; float s = 0.f;
    for (int k = 0; k < 256; k++){ float t = v1[o*256+k]; s += t*t; }
    ((float*)(ws + S1_OFF))[o] = g1[o] / sqrtf(s);
  } else if (r < 769){
    int o = r - 512; float s = 0.f;
    for (int k = 0; k < 256; k++){ float t = v2[o*256+k]; s += t*t; }
    ((float*)(ws + S2_OFF))[o] = g2[o] / sqrtf(s);
  }
}

// ---- precompute 2: pack normalized weights into MFMA B-fragment order (bf16) ----
__global__ void pack_kernel(const float* __restrict__ v0, const float* __restrict__ v1,
                            const float* __restrict__ v2, char* __restrict__ ws){
  int i = blockIdx.x * 256 + threadIdx.x;
  const float* s0 = (const float*)(ws + S0_OFF);
  const float* s1 = (const float*)(ws + S1_OFF);
  const float* s2 = (const float*)(ws + S2_OFF);
  if (i < 24576){                  // B0: 16 nt * 3 kt * 512
    int j = i & 7, l = (i >> 3) & 63, q = i >> 9;
    int kt = q % 3, nt = q / 3;
    int k = kt*32 + (l >> 4)*8 + j, col = nt*16 + (l & 15);
    float v = (k < 71) ? v0[col*71 + k] * s0[col] : 0.f;
    ((unsigned short*)(ws + B0_OFF))[i] = f2bf(v);
  } else if (i < 90112){           // B1: 16 nt * 8 kt * 512
    int e = i - 24576;
    int j = e & 7, l = (e >> 3) & 63, q = e >> 9;
    int kt = q & 7, nt = q >> 3;
    int k = kt*32 + (l >> 4)*8 + j, col = nt*16 + (l & 15);
    ((unsigned short*)(ws + B1_OFF))[e] = f2bf(v1[col*256 + k] * s1[col]);
  } else if (i < 155648){          // B2 (first 256 out rows)
    int e = i - 90112;
    int j = e & 7, l = (e >> 3) & 63, q = e >> 9;
    int kt = q & 7, nt = q >> 3;
    int k = kt*32 + (l >> 4)*8 + j, col = nt*16 + (l & 15);
    ((unsigned short*)(ws + B2_OFF))[e] = f2bf(v2[col*256 + k] * s2[col]);
  } else if (i < 155904){          // w2 last row, fp32
    int k = i - 155648;
    ((float*)(ws + W2L_OFF))[k] = v2[256*256 + k] * s2[256];
  }
}

// ---- precompute 3: table f32 -> packed bf16x2 (one uint per entry) ----
__global__ void tconv_kernel(const float* __restrict__ table, char* __restrict__ ws, int total){
  int i = blockIdx.x * 256 + threadIdx.x;
  if (i < total){
    float2 v = ((const float2*)table)[i];
    unsigned lo = ((unsigned)f2bf(v.x));
    unsigned hi = ((unsigned)f2bf(v.y)) << 16;
    ((unsigned*)(ws + TBF_OFF))[i] = lo | hi;
  }
}

// ============================================================================
// encode v2: issue ALL 32 gathers before consuming (ILP), bf16 table option.
// Writes bf16 features pre-packed in MFMA A-fragment order.
// ============================================================================
template<int USEBF>
__global__ __launch_bounds__(256, 4) void enc_kernel2(
    const float* __restrict__ xin, const float* __restrict__ table,
    char* __restrict__ ws, HashCfg cfg)
{
  __shared__ unsigned short fl[64][104];

  const int tid = threadIdx.x;
  const int p   = tid & 63;
  const int grp = tid >> 6;
  const int gp  = blockIdx.x * 64 + p;

  const float x0 = xin[gp*3], x1 = xin[gp*3+1], x2 = xin[gp*3+2];
  float xv[3] = {x0, x1, x2};
  const unsigned* __restrict__ tbf = (const unsigned*)(ws + TBF_OFF);

  // ---- issue phase: all 32 gathers for this thread's 4 levels ----
  unsigned vbf[4][8];
  float2   vf[4][8];
  float wxa[4], wya[4], wza[4];
  #pragma unroll
  for (int ii = 0; ii < 4; ii++){
    int lev = grp*4 + ii;
    int res = cfg.res[lev];
    float scl = (float)(res - 1);
    float px = x0*scl, py = x1*scl, pz = x2*scl;
    float fx = floorf(px), fy = floorf(py), fz = floorf(pz);
    wxa[ii] = px - fx; wya[ii] = py - fy; wza[ii] = pz - fz;
    unsigned cx0 = (unsigned)fx, cy0 = (unsigned)fy, cz0 = (unsigned)fz;
    unsigned r1 = (unsigned)(res + 1);
    bool hl = (cfg.hashed_mask >> lev) & 1;
    unsigned base = (unsigned)cfg.off[lev];
    #pragma unroll
    for (int c = 0; c < 8; c++){
      unsigned bx = (c >> 2) & 1, by = (c >> 1) & 1, bz = c & 1;
      unsigned cx = cx0 + bx, cy = cy0 + by, cz = cz0 + bz;
      unsigned idx = hl ? ((cx ^ (cy * 2654435761u) ^ (cz * 805459861u)) & TMASK)
                        : (cx + cy * r1 + cz * r1 * r1);
      if (USEBF) vbf[ii][c] = tbf[base + idx];
      else       vf[ii][c]  = *(const float2*)(table + (size_t)(base + idx) * 2u);
    }
  }

  // trig / input / K-pad (overlaps with gather latency)
  if (grp < 3){
    #pragma unroll
    for (int fi = 0; fi < 2; fi++){
      int f = grp*2 + fi;
      float fr = (float)(1 << f);
      #pragma unroll
      for (int d = 0; d < 3; d++){
        float a = xv[d] * fr;
        fl[p][3 + f*6 + d]     = f2bf(__sinf(a));
        fl[p][3 + f*6 + 3 + d] = f2bf(__cosf(a));
      }
    }
  } else {
    fl[p][0] = f2bf(x0); fl[p][1] = f2bf(x1); fl[p][2] = f2bf(x2);
    #pragma unroll
    for (int c = 71; c < 96; c++) fl[p][c] = 0;
  }

  // ---- consume phase ----
  #pragma unroll
  for (int ii = 0; ii < 4; ii++){
    int lev = grp*4 + ii;
    float wx = wxa[ii], wy = wya[ii], wz = wza[ii];
    float f0 = 0.f, f1 = 0.f;
    #pragma unroll
    for (int c = 0; c < 8; c++){
      unsigned bx = (c >> 2) & 1, by = (c >> 1) & 1, bz = c & 1;
      float w = (bx ? wx : 1.f - wx) * (by ? wy : 1.f - wy) * (bz ? wz : 1.f - wz);
      if (USEBF){
        unsigned u = vbf[ii][c];
        f0 += w * __uint_as_float(u << 16);
        f1 += w * __uint_as_float(u & 0xffff0000u);
      } else {
        f0 += w * vf[ii][c].x;
        f1 += w * vf[ii][c].y;
      }
    }
    fl[p][39 + 2*lev] = f2bf(f0);
    fl[p][40 + 2*lev] = f2bf(f1);
  }
  __syncthreads();

  // pack to global: 768 short8 per block, 3 per thread, coalesced stores
  short8* pA = (short8*)(ws + PACKA_OFF) + (size_t)blockIdx.x * 768;
  #pragma unroll
  for (int i = 0; i < 3; i++){
    int e = tid + 256*i;
    int lq = e & 63, q = e >> 6;
    int mt = q & 3, kt = q >> 2;
    int row = mt*16 + (lq & 15);
    int kb  = kt*32 + (lq >> 4)*8;
    pA[e] = *(const short8*)&fl[row][kb];
  }
}

// ============================================================================
// MLP kernel (unchanged from round 2)
// ============================================================================
__global__ __launch_bounds__(256, 4) void mlp_kernel(
    const char* __restrict__ ws,
    const float* __restrict__ b0, const float* __restrict__ b1, const float* __restrict__ b2,
    float* __restrict__ out)
{
  __shared__ unsigned short buf[64 * 256];
  __shared__ float colsc[4][64];

  const int tid = threadIdx.x;
  const int l  = tid & 63;
  const int wv = tid >> 6;
  const int lr = l & 15;
  const int lh = l >> 4;

  const short8* Ap  = (const short8*)(ws + PACKA_OFF) + (size_t)blockIdx.x * 768;
  const short8* B0p = (const short8*)(ws + B0_OFF);
  const short8* B1p = (const short8*)(ws + B1_OFF);
  const short8* B2p = (const short8*)(ws + B2_OFF);

  auto stB = [&](int row, int col, float v){
    buf[row*256 + (col ^ ((row & 7) << 3))] = f2bf(v);
  };
  auto ldB = [&](int row, int kb) -> short8 {
    return *(const short8*)&buf[row*256 + (kb ^ ((row & 7) << 3))];
  };

  { // layer 0
    f32x4 acc[4][4];
    #pragma unroll
    for (int a = 0; a < 4; a++)
      #pragma unroll
      for (int b = 0; b < 4; b++) acc[a][b] = (f32x4){0.f,0.f,0.f,0.f};
    #pragma unroll
    for (int kt = 0; kt < 3; kt++){
      short8 af[4];
      #pragma unroll
      for (int mt = 0; mt < 4; mt++) af[mt] = Ap[(kt*4 + mt)*64 + l];
      #pragma unroll
      for (int nt = 0; nt < 4; nt++){
        short8 bf = B0p[((wv*4 + nt)*3 + kt)*64 + l];
        #pragma unroll
        for (int mt = 0; mt < 4; mt++)
          acc[mt][nt] = __builtin_amdgcn_mfma_f32_16x16x32_bf16(af[mt], bf, acc[mt][nt], 0, 0, 0);
      }
    }
    float bb[4];
    #pragma unroll
    for (int nt = 0; nt < 4; nt++) bb[nt] = b0[wv*64 + nt*16 + lr];
    #pragma unroll
    for (int mt = 0; mt < 4; mt++)
      #pragma unroll
      for (int nt = 0; nt < 4; nt++){
        int c = wv*64 + nt*16 + lr;
        #pragma unroll
        for (int j = 0; j < 4; j++)
          stB(mt*16 + lh*4 + j, c, softplus100_fast(acc[mt][nt][j] + bb[nt]));
      }
  }
  __syncthreads();

  { // layer 1
    f32x4 acc[4][4];
    #pragma unroll
    for (int a = 0; a < 4; a++)
      #pragma unroll
      for (int b = 0; b < 4; b++) acc[a][b] = (f32x4){0.f,0.f,0.f,0.f};
    #pragma unroll
    for (int kt = 0; kt < 8; kt++){
      short8 af[4];
      #pragma unroll
      for (int mt = 0; mt < 4; mt++) af[mt] = ldB(mt*16 + lr, kt*32 + lh*8);
      #pragma unroll
      for (int nt = 0; nt < 4; nt++){
        short8 bf = B1p[((wv*4 + nt)*8 + kt)*64 + l];
        #pragma unroll
        for (int mt = 0; mt < 4; mt++)
          acc[mt][nt] = __builtin_amdgcn_mfma_f32_16x16x32_bf16(af[mt], bf, acc[mt][nt], 0, 0, 0);
      }
    }
    __syncthreads();
    float bb[4];
    #pragma unroll
    for (int nt = 0; nt < 4; nt++) bb[nt] = b1[wv*64 + nt*16 + lr];
    #pragma unroll
    for (int mt = 0; mt < 4; mt++)
      #pragma unroll
      for (int nt = 0; nt < 4; nt++){
        int c = wv*64 + nt*16 + lr;
        #pragma unroll
        for (int j = 0; j < 4; j++)
          stB(mt*16 + lh*4 + j, c, softplus100_fast(acc[mt][nt][j] + bb[nt]));
      }
  }
  __syncthreads();

  {
    const float* w2l = (const float*)(ws + W2L_OFF);
    float s = 0.f;
    #pragma unroll
    for (int q = 0; q < 8; q++){
      short8 h = ldB(l, wv*64 + q*8);
      #pragma unroll
      for (int j = 0; j < 8; j++)
        s += bf2f((unsigned short)h[j]) * w2l[wv*64 + q*8 + j];
    }
    colsc[wv][l] = s;
  }

  { // layer 2
    f32x4 acc[4][4];
    #pragma unroll
    for (int a = 0; a < 4; a++)
      #pragma unroll
      for (int b = 0; b < 4; b++) acc[a][b] = (f32x4){0.f,0.f,0.f,0.f};
    #pragma unroll
    for (int kt = 0; kt < 8; kt++){
      short8 af[4];
      #pragma unroll
      for (int mt = 0; mt < 4; mt++) af[mt] = ldB(mt*16 + lr, kt*32 + lh*8);
      #pragma unroll
      for (int nt = 0; nt < 4; nt++){
        short8 bf = B2p[((wv*4 + nt)*8 + kt)*64 + l];
        #pragma unroll
        for (int mt = 0; mt < 4; mt++)
          acc[mt][nt] = __builtin_amdgcn_mfma_f32_16x16x32_bf16(af[mt], bf, acc[mt][nt], 0, 0, 0);
      }
    }
    __syncthreads();
    float bb[4];
    #pragma unroll
    for (int nt = 0; nt < 4; nt++) bb[nt] = b2[wv*64 + nt*16 + lr];
    #pragma unroll
    for (int mt = 0; mt < 4; mt++)
      #pragma unroll
      for (int nt = 0; nt < 4; nt++){
        int c = wv*64 + nt*16 + lr;
        #pragma unroll
        for (int j = 0; j < 4; j++){
          int r = mt*16 + lh*4 + j;
          out[(size_t)(blockIdx.x*64 + r)*257 + c] = acc[mt][nt][j] + bb[nt];
        }
      }
    if (tid < 64)
      out[(size_t)(blockIdx.x*64 + tid)*257 + 256] =
        colsc[0][tid] + colsc[1][tid] + colsc[2][tid] + colsc[3][tid] + b2[256];
  }
}

// ============================================================================
// Fallback: fused kernel (only if ws too small for packed A)
// ============================================================================
__global__ __launch_bounds__(256, 2) void nerf_fused(
    const float* __restrict__ xin, const float* __restrict__ table,
    const char* __restrict__ ws,
    const float* __restrict__ b0, const float* __restrict__ b1, const float* __restrict__ b2,
    float* __restrict__ out, HashCfg cfg)
{
  __shared__ unsigned short bufA[64 * 128];
  __shared__ unsigned short bufB[64 * 256];

  const int tid = threadIdx.x;
  const int p   = tid & 63;
  const int grp = tid >> 6;
  const int gp  = blockIdx.x * 64 + p;

  const float x0 = xin[gp*3], x1 = xin[gp*3+1], x2 = xin[gp*3+2];

  auto stA = [&](int row, int col, float v){
    bufA[row*128 + (col ^ ((row & 7) << 3))] = f2bf(v);
  };
  auto stB = [&](int row, int col, float v){
    bufB[row*256 + (col ^ ((row & 7) << 3))] = f2bf(v);
  };

  if (grp == 0){
    stA(p, 0, x0); stA(p, 1, x1); stA(p, 2, x2);
    float xv[3] = {x0, x1, x2};
    #pragma unroll
    for (int f = 0; f < 6; f++){
      float fr = (float)(1 << f);
      #pragma unroll
      for (int d = 0; d < 3; d++){
        float a = xv[d] * fr;
        stA(p, 3 + f*6 + d,     sinf(a));
        stA(p, 3 + f*6 + 3 + d, cosf(a));
      }
    }
    for (int c = 71; c < 96; c++) stA(p, c, 0.f);
  }
  for (int ii = 0; ii < 4; ii++){
    int lv = grp*4 + ii;
    int res = cfg.res[lv];
    float scl = (float)(res - 1);
    float px = x0*scl, py = x1*scl, pz = x2*scl;
    float fx = floorf(px), fy = floorf(py), fz = floorf(pz);
    float wx = px - fx, wy = py - fy, wz = pz - fz;
    unsigned cx0 = (unsigned)fx, cy0 = (unsigned)fy, cz0 = (unsigned)fz;
    unsigned r1 = (unsigned)(res + 1);
    bool hl = (cfg.hashed_mask >> lv) & 1;
    unsigned base = (unsigned)cfg.off[lv];
    float f0 = 0.f, f1 = 0.f;
    #pragma unroll
    for (int c = 0; c < 8; c++){
      unsigned bx = (c >> 2) & 1, by = (c >> 1) & 1, bz = c & 1;
      unsigned cx = cx0 + bx, cy = cy0 + by, cz = cz0 + bz;
      unsigned idx = hl ? ((cx ^ (cy * 2654435761u) ^ (cz * 805459861u)) & TMASK)
                        : (cx + cy * r1 + cz * r1 * r1);
      const float2 fv = *(const float2*)(table + (size_t)(base + idx) * 2u);
      float w = (bx ? wx : 1.f - wx) * (by ? wy : 1.f - wy) * (bz ? wz : 1.f - wz);
      f0 += w * fv.x; f1 += w * fv.y;
    }
    stA(p, 39 + 2*lv, f0);
    stA(p, 40 + 2*lv, f1);
  }
  __syncthreads();

  const int l  = tid & 63;
  const int lr = l & 15;
  const int lh = l >> 4;
  const int wv = grp;
  const short8* B0p = (const short8*)(ws + B0_OFF);
  const short8* B1p = (const short8*)(ws + B1_OFF);
  const short8* B2p = (const short8*)(ws + B2_OFF);

  auto ldA = [&](int row, int kb) -> short8 {
    return *(const short8*)&bufA[row*128 + (kb ^ ((row & 7) << 3))];
  };
  auto ldB = [&](int row, int kb) -> short8 {
    return *(const short8*)&bufB[row*256 + (kb ^ ((row & 7) << 3))];
  };

  {
    f32x4 acc[4][4];
    #pragma unroll
    for (int a = 0; a < 4; a++)
      #pragma unroll
      for (int b = 0; b < 4; b++) acc[a][b] = (f32x4){0.f,0.f,0.f,0.f};
    for (int kt = 0; kt < 3; kt++){
      short8 af[4];
      #pragma unroll
      for (int mt = 0; mt < 4; mt++) af[mt] = ldA(mt*16 + lr, kt*32 + lh*8);
      #pragma unroll
      for (int nt = 0; nt < 4; nt++){
        short8 bf = B0p[((wv*4 + nt)*3 + kt)*64 + l];
        #pragma unroll
        for (int mt = 0; mt < 4; mt++)
          acc[mt][nt] = __builtin_amdgcn_mfma_f32_16x16x32_bf16(af[mt], bf, acc[mt][nt], 0, 0, 0);
      }
    }
    #pragma unroll
    for (int mt = 0; mt < 4; mt++)
      #pragma unroll
      for (int nt = 0; nt < 4; nt++){
        int c = wv*64 + nt*16 + lr;
        float bbv = b0[c];
        #pragma unroll
        for (int j = 0; j < 4; j++)
          stB(mt*16 + lh*4 + j, c, softplus100(acc[mt][nt][j] + bbv));
      }
  }
  __syncthreads();

  {
    f32x4 acc[4][4];
    #pragma unroll
    for (int a = 0; a < 4; a++)
      #pragma unroll
      for (int b = 0; b < 4; b++) acc[a][b] = (f32x4){0.f,0.f,0.f,0.f};
    for (int kt = 0; kt < 8; kt++){
      short8 af[4];
      #pragma unroll
      for (int mt = 0; mt < 4; mt++) af[mt] = ldB(mt*16 + lr, kt*32 + lh*8);
      #pragma unroll
      for (int nt = 0; nt < 4; nt++){
        short8 bf = B1p[((wv*4 + nt)*8 + kt)*64 + l];
        #pragma unroll
        for (int mt = 0; mt < 4; mt++)
          acc[mt][nt] = __builtin_amdgcn_mfma_f32_16x16x32_bf16(af[mt], bf, acc[mt][nt], 0, 0, 0);
      }
    }
    __syncthreads();
    #pragma unroll
    for (int mt = 0; mt < 4; mt++)
      #pragma unroll
      for (int nt = 0; nt < 4; nt++){
        int c = wv*64 + nt*16 + lr;
        float bbv = b1[c];
        #pragma unroll
        for (int j = 0; j < 4; j++)
          stB(mt*16 + lh*4 + j, c, softplus100(acc[mt][nt][j] + bbv));
      }
  }
  __syncthreads();

  {
    f32x4 acc[4][4];
    #pragma unroll
    for (int a = 0; a < 4; a++)
      #pragma unroll
      for (int b = 0; b < 4; b++) acc[a][b] = (f32x4){0.f,0.f,0.f,0.f};
    for (int kt = 0; kt < 8; kt++){
      short8 af[4];
      #pragma unroll
      for (int mt = 0; mt < 4; mt++) af[mt] = ldB(mt*16 + lr, kt*32 + lh*8);
      #pragma unroll
      for (int nt = 0; nt < 4; nt++){
        short8 bf = B2p[((wv*4 + nt)*8 + kt)*64 + l];
        #pragma unroll
        for (int mt = 0; mt < 4; mt++)
          acc[mt][nt] = __builtin_amdgcn_mfma_f32_16x16x32_bf16(af[mt], bf, acc[mt][nt], 0, 0, 0);
      }
    }
    #pragma unroll
    for (int mt = 0; mt < 4; mt++)
      #pragma unroll
      for (int nt = 0; nt < 4; nt++){
        int c = wv*64 + nt*16 + lr;
        float bbv = b2[c];
        #pragma unroll
        for (int j = 0; j < 4; j++){
          int r = mt*16 + lh*4 + j;
          out[(size_t)(blockIdx.x*64 + r)*257 + c] = acc[mt][nt][j] + bbv;
        }
      }
  }
  if (tid < 64){
    const float* w2l = (const float*)(ws + W2L_OFF);
    float dot = b2[256];
    for (int k8 = 0; k8 < 32; k8++){
      int elem = (k8*8) ^ ((p & 7) << 3);
      short8 hv = *(const short8*)&bufB[p*256 + elem];
      #pragma unroll
      for (int j = 0; j < 8; j++)
        dot += bf2f((unsigned short)hv[j]) * w2l[k8*8 + j];
    }
    out[(size_t)gp * 257 + 256] = dot;
  }
}

// ---- host: replicate reference's double-precision level config exactly ----
static HashCfg make_cfg(){
  HashCfg c;
  double pls = exp2(log2(2048.0 / 16.0) / 15.0);
  long long off = 0;
  unsigned mask = 0;
  for (int l = 0; l < 16; l++){
    int r = (int)ceil(16.0 * pow(pls, (double)l));
    c.res[l] = r;
    c.off[l] = (int)off;
    double n3 = (double)(r + 1) * (double)(r + 1) * (double)(r + 1);
    long long size;
    if (n3 > 524288.0){ mask |= (1u << l); }
    size = (long long)(ceil(n3 / 8.0) * 8.0);
    if (size > 524288) size = 524288;
    off += size;
  }
  c.hashed_mask = mask;
  c.total = (int)off;
  return c;
}

extern "C" void kernel_launch(void* const* d_in, const int* in_sizes, int n_in,
                              void* d_out, int out_size, void* d_ws, size_t ws_size,
                              hipStream_t stream) {
  const float* x     = (const float*)d_in[0];
  const float* table = (const float*)d_in[1];
  const float* v0 = (const float*)d_in[2];
  const float* g0 = (const float*)d_in[3];
  const float* b0 = (const float*)d_in[4];
  const float* v1 = (const float*)d_in[5];
  const float* g1 = (const float*)d_in[6];
  const float* b1 = (const float*)d_in[7];
  const float* v2 = (const float*)d_in[8];
  const float* g2 = (const float*)d_in[9];
  const float* b2 = (const float*)d_in[10];
  float* out = (float*)d_out;
  char* ws = (char*)d_ws;

  HashCfg cfg = make_cfg();
  size_t ws_need_bf = (size_t)TBF_OFF + (size_t)cfg.total * 4u;

  hipLaunchKernelGGL(scale_kernel, dim3(4), dim3(256), 0, stream, v0, g0, v1, g1, v2, g2, ws);
  hipLaunchKernelGGL(pack_kernel, dim3(609), dim3(256), 0, stream, v0, v1, v2, ws);

  if (ws_size >= ws_need_bf){
    hipLaunchKernelGGL(tconv_kernel, dim3((cfg.total + 255) / 256), dim3(256), 0, stream,
                       table, ws, cfg.total);
    hipLaunchKernelGGL((enc_kernel2<1>), dim3(N_POINTS / 64), dim3(256), 0, stream,
                       x, table, ws, cfg);
    hipLaunchKernelGGL(mlp_kernel, dim3(N_POINTS / 64), dim3(256), 0, stream,
                       ws, b0, b1, b2, out);
  } else if (ws_size >= WS_NEED){
    hipLaunchKernelGGL((enc_kernel2<0>), dim3(N_POINTS / 64), dim3(256), 0, stream,
                       x, table, ws, cfg);
    hipLaunchKernelGGL(mlp_kernel, dim3(N_POINTS / 64), dim3(256), 0, stream,
                       ws, b0, b1, b2, out);
  } else {
    hipLaunchKernelGGL(nerf_fused, dim3(N_POINTS / 64), dim3(256), 0, stream,
                       x, table, ws, b0, b1, b2, out, cfg);
  }
}

// Round 4
// 870.245 us; speedup vs baseline: 1.5320x; 1.2261x over previous
//
#include <hip/hip_runtime.h>
#include <cmath>

typedef float f32x4 __attribute__((ext_vector_type(4)));
typedef short short8 __attribute__((ext_vector_type(8)));

#define N_POINTS 524288
#define TMASK 0x7FFFFu   // T_MAX-1, hashed levels all have size 2^19

struct HashCfg { int res[16]; int off[16]; unsigned hashed_mask; int total; };

// ---- ws layout (bytes) ----
#define S0_OFF   0        // 256 f32 scale (g/||v||) layer0
#define S1_OFF   1024
#define S2_OFF   2048     // 257 f32
#define W2L_OFF  3328     // 256 f32: normalized last row of v2
#define B0_OFF   4608     // 16nt*3kt*64l*8j bf16 = 49152 B
#define B1_OFF   (B0_OFF + 49152)
#define B2_OFF   (B1_OFF + 131072)
#define TBF_OFF  (B2_OFF + 131072)   // bf16x2 table copy (~24.5 MB)

__device__ inline unsigned short f2bf(float f){
  unsigned u = __float_as_uint(f);
  u = (u + 0x7FFFu + ((u >> 16) & 1u)) >> 16;
  return (unsigned short)u;
}
__device__ inline float bf2f(unsigned short h){
  return __uint_as_float(((unsigned)h) << 16);
}
// fast softplus(beta=100): |err| < 1e-7 absolute, far below bf16 storage rounding
__device__ inline float softplus100_fast(float x){
  float y = 100.f * x;
  return 0.01f * (fmaxf(y, 0.f) + __logf(1.f + __expf(-fabsf(y))));
}

// ---- precompute 1: weight-norm row scales ----
__global__ void scale_kernel(const float* __restrict__ v0, const float* __restrict__ g0,
                             const float* __restrict__ v1, const float* __restrict__ g1,
                             const float* __restrict__ v2, const float* __restrict__ g2,
                             char* __restrict__ ws){
  int r = blockIdx.x * 256 + threadIdx.x;
  if (r < 256){
    float s = 0.f;
    for (int k = 0; k < 71; k++){ float t = v0[r*71+k]; s += t*t; }
    ((float*)(ws + S0_OFF))[r] = g0[r] / sqrtf(s);
  } else if (r < 512){
    int o = r - 256; float s = 0.f;
    for (int k = 0; k < 256; k++){ float t = v1[o*256+k]; s += t*t; }
    ((float*)(ws + S1_OFF))[o] = g1[o] / sqrtf(s);
  } else if (r < 769){
    int o = r - 512; float s = 0.f;
    for (int k = 0; k < 256; k++){ float t = v2[o*256+k]; s += t*t; }
    ((float*)(ws + S2_OFF))[o] = g2[o] / sqrtf(s);
  }
}

// ---- precompute 2: pack normalized weights into MFMA B-fragment order (bf16) ----
// element (nt,kt,l,j): k = kt*32 + (l>>4)*8 + j ; col = nt*16 + (l&15); value = Wn[col][k]
__global__ void pack_kernel(const float* __restrict__ v0, const float* __restrict__ v1,
                            const float* __restrict__ v2, char* __restrict__ ws){
  int i = blockIdx.x * 256 + threadIdx.x;
  const float* s0 = (const float*)(ws + S0_OFF);
  const float* s1 = (const float*)(ws + S1_OFF);
  const float* s2 = (const float*)(ws + S2_OFF);
  if (i < 24576){                  // B0: 16 nt * 3 kt * 512
    int j = i & 7, l = (i >> 3) & 63, q = i >> 9;
    int kt = q % 3, nt = q / 3;
    int k = kt*32 + (l >> 4)*8 + j, col = nt*16 + (l & 15);
    float v = (k < 71) ? v0[col*71 + k] * s0[col] : 0.f;
    ((unsigned short*)(ws + B0_OFF))[i] = f2bf(v);
  } else if (i < 90112){           // B1: 16 nt * 8 kt * 512
    int e = i - 24576;
    int j = e & 7, l = (e >> 3) & 63, q = e >> 9;
    int kt = q & 7, nt = q >> 3;
    int k = kt*32 + (l >> 4)*8 + j, col = nt*16 + (l & 15);
    ((unsigned short*)(ws + B1_OFF))[e] = f2bf(v1[col*256 + k] * s1[col]);
  } else if (i < 155648){          // B2 (first 256 out rows)
    int e = i - 90112;
    int j = e & 7, l = (e >> 3) & 63, q = e >> 9;
    int kt = q & 7, nt = q >> 3;
    int k = kt*32 + (l >> 4)*8 + j, col = nt*16 + (l & 15);
    ((unsigned short*)(ws + B2_OFF))[e] = f2bf(v2[col*256 + k] * s2[col]);
  } else if (i < 155904){          // w2 last row, fp32
    int k = i - 155648;
    ((float*)(ws + W2L_OFF))[k] = v2[256*256 + k] * s2[256];
  }
}

// ---- precompute 3: table f32 -> packed bf16x2 (one uint per entry) ----
__global__ void tconv_kernel(const float* __restrict__ table, char* __restrict__ ws, int total){
  int i = blockIdx.x * 256 + threadIdx.x;
  if (i < total){
    float2 v = ((const float2*)table)[i];
    unsigned lo = ((unsigned)f2bf(v.x));
    unsigned hi = ((unsigned)f2bf(v.y)) << 16;
    ((unsigned*)(ws + TBF_OFF))[i] = lo | hi;
  }
}

// ============================================================================
// Fused v2: 64 points per block, 4 waves. Gather ILP + MFMA MLP + staged
// full-line output writes. Blocks at different phases overlap VMEM vs MFMA.
// ============================================================================
template<int USEBF>
__global__ __launch_bounds__(256, 4) void fused2(
    const float* __restrict__ xin, const float* __restrict__ table,
    char* __restrict__ ws,
    const float* __restrict__ b0, const float* __restrict__ b1, const float* __restrict__ b2,
    float* __restrict__ out, HashCfg cfg)
{
  __shared__ unsigned short buf[64 * 256];  // swizzled: elem(row,col) at col^((row&7)<<3)
  __shared__ float colsc[4][64];

  const int tid = threadIdx.x;
  const int p   = tid & 63;        // local point / row
  const int grp = tid >> 6;        // wave id
  const int gp  = blockIdx.x * 64 + p;

  const float x0 = xin[gp*3], x1 = xin[gp*3+1], x2 = xin[gp*3+2];
  const unsigned* __restrict__ tbf = (const unsigned*)(ws + TBF_OFF);

  auto stB = [&](int row, int col, float v){
    buf[row*256 + (col ^ ((row & 7) << 3))] = f2bf(v);
  };
  auto ldB = [&](int row, int kb) -> short8 {
    return *(const short8*)&buf[row*256 + (kb ^ ((row & 7) << 3))];
  };

  // ---------- phase E: features ----------
  {
    float wxa[4], wya[4], wza[4];
    unsigned vb[2][8];
    float2   vf2[2][8];

    auto issue_level = [&](int ii, int slot){
      int lev = grp*4 + ii;
      int res = cfg.res[lev];
      float scl = (float)(res - 1);
      float px = x0*scl, py = x1*scl, pz = x2*scl;
      float fx = floorf(px), fy = floorf(py), fz = floorf(pz);
      wxa[ii] = px - fx; wya[ii] = py - fy; wza[ii] = pz - fz;
      unsigned cx0 = (unsigned)fx, cy0 = (unsigned)fy, cz0 = (unsigned)fz;
      unsigned r1 = (unsigned)(res + 1);
      bool hl = (cfg.hashed_mask >> lev) & 1;
      unsigned base = (unsigned)cfg.off[lev];
      #pragma unroll
      for (int c = 0; c < 8; c++){
        unsigned bx = (c >> 2) & 1, by = (c >> 1) & 1, bz = c & 1;
        unsigned cx = cx0 + bx, cy = cy0 + by, cz = cz0 + bz;
        unsigned idx = hl ? ((cx ^ (cy * 2654435761u) ^ (cz * 805459861u)) & TMASK)
                          : (cx + cy * r1 + cz * r1 * r1);
        if (USEBF) vb[slot][c]  = tbf[base + idx];
        else       vf2[slot][c] = *(const float2*)(table + (size_t)(base + idx) * 2u);
      }
    };
    auto consume_level = [&](int ii, int slot){
      int lev = grp*4 + ii;
      float wx = wxa[ii], wy = wya[ii], wz = wza[ii];
      float f0 = 0.f, f1 = 0.f;
      #pragma unroll
      for (int c = 0; c < 8; c++){
        unsigned bx = (c >> 2) & 1, by = (c >> 1) & 1, bz = c & 1;
        float w = (bx ? wx : 1.f - wx) * (by ? wy : 1.f - wy) * (bz ? wz : 1.f - wz);
        if (USEBF){
          unsigned u = vb[slot][c];
          f0 += w * __uint_as_float(u << 16);
          f1 += w * __uint_as_float(u & 0xffff0000u);
        } else {
          f0 += w * vf2[slot][c].x;
          f1 += w * vf2[slot][c].y;
        }
      }
      stB(p, 39 + 2*lev, f0);
      stB(p, 40 + 2*lev, f1);
    };

    issue_level(0, 0); issue_level(1, 1);

    // trig / input / K-pad overlaps gather latency
    if (grp < 3){
      float xv[3] = {x0, x1, x2};
      #pragma unroll
      for (int fi = 0; fi < 2; fi++){
        int f = grp*2 + fi;
        float fr = (float)(1 << f);
        #pragma unroll
        for (int d = 0; d < 3; d++){
          float a = xv[d] * fr;
          stB(p, 3 + f*6 + d,     __sinf(a));
          stB(p, 3 + f*6 + 3 + d, __cosf(a));
        }
      }
    } else {
      stB(p, 0, x0); stB(p, 1, x1); stB(p, 2, x2);
      #pragma unroll
      for (int c = 71; c < 96; c++)
        buf[p*256 + (c ^ ((p & 7) << 3))] = 0;
    }

    consume_level(0, 0); consume_level(1, 1);
    issue_level(2, 0);   issue_level(3, 1);
    consume_level(2, 0); consume_level(3, 1);
  }
  __syncthreads();

  // ---------- MFMA phases ----------
  const int l  = tid & 63;
  const int lr = l & 15;    // A-row / C-col within tile
  const int lh = l >> 4;    // k-group; C-row = lh*4 + j
  const int wv = grp;       // wave owns output cols [wv*64, wv*64+64)
  const short8* B0p = (const short8*)(ws + B0_OFF);
  const short8* B1p = (const short8*)(ws + B1_OFF);
  const short8* B2p = (const short8*)(ws + B2_OFF);

  { // ----- layer 0: h0[64x96] @ W0^T -----
    f32x4 acc[4][4];
    #pragma unroll
    for (int a = 0; a < 4; a++)
      #pragma unroll
      for (int b = 0; b < 4; b++) acc[a][b] = (f32x4){0.f,0.f,0.f,0.f};
    #pragma unroll
    for (int kt = 0; kt < 3; kt++){
      short8 af[4];
      #pragma unroll
      for (int mt = 0; mt < 4; mt++) af[mt] = ldB(mt*16 + lr, kt*32 + lh*8);
      #pragma unroll
      for (int nt = 0; nt < 4; nt++){
        short8 bf = B0p[((wv*4 + nt)*3 + kt)*64 + l];
        #pragma unroll
        for (int mt = 0; mt < 4; mt++)
          acc[mt][nt] = __builtin_amdgcn_mfma_f32_16x16x32_bf16(af[mt], bf, acc[mt][nt], 0, 0, 0);
      }
    }
    __syncthreads();   // all feature reads complete before h1 overwrites buf
    float bb[4];
    #pragma unroll
    for (int nt = 0; nt < 4; nt++) bb[nt] = b0[wv*64 + nt*16 + lr];
    #pragma unroll
    for (int mt = 0; mt < 4; mt++)
      #pragma unroll
      for (int nt = 0; nt < 4; nt++){
        int c = wv*64 + nt*16 + lr;
        #pragma unroll
        for (int j = 0; j < 4; j++)
          stB(mt*16 + lh*4 + j, c, softplus100_fast(acc[mt][nt][j] + bb[nt]));
      }
  }
  __syncthreads();

  { // ----- layer 1 -----
    f32x4 acc[4][4];
    #pragma unroll
    for (int a = 0; a < 4; a++)
      #pragma unroll
      for (int b = 0; b < 4; b++) acc[a][b] = (f32x4){0.f,0.f,0.f,0.f};
    #pragma unroll
    for (int kt = 0; kt < 8; kt++){
      short8 af[4];
      #pragma unroll
      for (int mt = 0; mt < 4; mt++) af[mt] = ldB(mt*16 + lr, kt*32 + lh*8);
      #pragma unroll
      for (int nt = 0; nt < 4; nt++){
        short8 bf = B1p[((wv*4 + nt)*8 + kt)*64 + l];
        #pragma unroll
        for (int mt = 0; mt < 4; mt++)
          acc[mt][nt] = __builtin_amdgcn_mfma_f32_16x16x32_bf16(af[mt], bf, acc[mt][nt], 0, 0, 0);
      }
    }
    __syncthreads();   // all h1 reads complete before h2 overwrites buf
    float bb[4];
    #pragma unroll
    for (int nt = 0; nt < 4; nt++) bb[nt] = b1[wv*64 + nt*16 + lr];
    #pragma unroll
    for (int mt = 0; mt < 4; mt++)
      #pragma unroll
      for (int nt = 0; nt < 4; nt++){
        int c = wv*64 + nt*16 + lr;
        #pragma unroll
        for (int j = 0; j < 4; j++)
          stB(mt*16 + lh*4 + j, c, softplus100_fast(acc[mt][nt][j] + bb[nt]));
      }
  }
  __syncthreads();  // h2 visible to all

  // last-col partials: thread (wv,l) handles row l, cols [wv*64, wv*64+64)
  {
    const float* w2l = (const float*)(ws + W2L_OFF);
    float s = 0.f;
    #pragma unroll
    for (int q = 0; q < 8; q++){
      short8 h = ldB(l, wv*64 + q*8);
      #pragma unroll
      for (int j = 0; j < 8; j++)
        s += bf2f((unsigned short)h[j]) * w2l[wv*64 + q*8 + j];
    }
    colsc[wv][l] = s;
  }

  { // ----- layer 2 + staged full-line output writes -----
    f32x4 acc[4][4];
    #pragma unroll
    for (int a = 0; a < 4; a++)
      #pragma unroll
      for (int b = 0; b < 4; b++) acc[a][b] = (f32x4){0.f,0.f,0.f,0.f};
    #pragma unroll
    for (int kt = 0; kt < 8; kt++){
      short8 af[4];
      #pragma unroll
      for (int mt = 0; mt < 4; mt++) af[mt] = ldB(mt*16 + lr, kt*32 + lh*8);
      #pragma unroll
      for (int nt = 0; nt < 4; nt++){
        short8 bf = B2p[((wv*4 + nt)*8 + kt)*64 + l];
        #pragma unroll
        for (int mt = 0; mt < 4; mt++)
          acc[mt][nt] = __builtin_amdgcn_mfma_f32_16x16x32_bf16(af[mt], bf, acc[mt][nt], 0, 0, 0);
      }
    }
    float bb[4];
    #pragma unroll
    for (int nt = 0; nt < 4; nt++) bb[nt] = b2[wv*64 + nt*16 + lr];
    const float b2last = b2[256];

    // 4 rounds: stage 16 rows x 257 f32 in LDS (reusing buf), write coalesced
    float* st = (float*)buf;                 // 16*257*4 = 16448 B <= 32768 B
    #pragma unroll
    for (int r16 = 0; r16 < 4; r16++){
      __syncthreads();   // round 0: also guards "all layer-2/colsc LDS reads done"
      #pragma unroll
      for (int nt = 0; nt < 4; nt++){
        int c = wv*64 + nt*16 + lr;
        #pragma unroll
        for (int j = 0; j < 4; j++)
          st[(lh*4 + j)*257 + c] = acc[r16][nt][j] + bb[nt];
      }
      if (tid < 16){
        int gr = r16*16 + tid;
        st[tid*257 + 256] = colsc[0][gr] + colsc[1][gr] + colsc[2][gr] + colsc[3][gr] + b2last;
      }
      __syncthreads();
      float4* dst4 = (float4*)(out + (size_t)(blockIdx.x*64 + r16*16) * 257);
      const float4* src4 = (const float4*)st;
      #pragma unroll 5
      for (int i = tid; i < 1028; i += 256) dst4[i] = src4[i];
    }
  }
}

// ---- host: replicate reference's double-precision level config exactly ----
static HashCfg make_cfg(){
  HashCfg c;
  double pls = exp2(log2(2048.0 / 16.0) / 15.0);
  long long off = 0;
  unsigned mask = 0;
  for (int l = 0; l < 16; l++){
    int r = (int)ceil(16.0 * pow(pls, (double)l));
    c.res[l] = r;
    c.off[l] = (int)off;
    double n3 = (double)(r + 1) * (double)(r + 1) * (double)(r + 1);
    long long size;
    if (n3 > 524288.0){ mask |= (1u << l); }
    size = (long long)(ceil(n3 / 8.0) * 8.0);
    if (size > 524288) size = 524288;
    off += size;
  }
  c.hashed_mask = mask;
  c.total = (int)off;
  return c;
}

extern "C" void kernel_launch(void* const* d_in, const int* in_sizes, int n_in,
                              void* d_out, int out_size, void* d_ws, size_t ws_size,
                              hipStream_t stream) {
  const float* x     = (const float*)d_in[0];
  const float* table = (const float*)d_in[1];
  const float* v0 = (const float*)d_in[2];
  const float* g0 = (const float*)d_in[3];
  const float* b0 = (const float*)d_in[4];
  const float* v1 = (const float*)d_in[5];
  const float* g1 = (const float*)d_in[6];
  const float* b1 = (const float*)d_in[7];
  const float* v2 = (const float*)d_in[8];
  const float* g2 = (const float*)d_in[9];
  const float* b2 = (const float*)d_in[10];
  float* out = (float*)d_out;
  char* ws = (char*)d_ws;

  HashCfg cfg = make_cfg();
  size_t ws_need_bf = (size_t)TBF_OFF + (size_t)cfg.total * 4u;

  hipLaunchKernelGGL(scale_kernel, dim3(4), dim3(256), 0, stream, v0, g0, v1, g1, v2, g2, ws);
  hipLaunchKernelGGL(pack_kernel, dim3(609), dim3(256), 0, stream, v0, v1, v2, ws);

  if (ws_size >= ws_need_bf){
    hipLaunchKernelGGL(tconv_kernel, dim3((cfg.total + 255) / 256), dim3(256), 0, stream,
                       table, ws, cfg.total);
    hipLaunchKernelGGL((fused2<1>), dim3(N_POINTS / 64), dim3(256), 0, stream,
                       x, table, ws, b0, b1, b2, out, cfg);
  } else {
    hipLaunchKernelGGL((fused2<0>), dim3(N_POINTS / 64), dim3(256), 0, stream,
                       x, table, ws, b0, b1, b2, out, cfg);
  }
}

// Round 5
// 789.106 us; speedup vs baseline: 1.6896x; 1.1028x over previous
//
#include <hip/hip_runtime.h>
#include <cmath>

typedef float f32x4 __attribute__((ext_vector_type(4)));
typedef short short8 __attribute__((ext_vector_type(8)));

#define N_POINTS 524288
#define TMASK 0x7FFFFu   // T_MAX-1, hashed levels all have size 2^19
#define NCELLS 32768     // 32^3 Morton cells

struct HashCfg { int res[16]; int off[16]; unsigned hashed_mask; int total; };

// ---- ws layout (bytes) ----
#define S0_OFF   0        // 256 f32 scale (g/||v||) layer0
#define S1_OFF   1024
#define S2_OFF   2048     // 257 f32
#define W2L_OFF  3328     // 256 f32: normalized last row of v2
#define B0_OFF   4608     // 16nt*3kt*64l*8j bf16 = 49152 B
#define B1_OFF   (B0_OFF + 49152)
#define B2_OFF   (B1_OFF + 131072)
#define TBF_OFF  (B2_OFF + 131072)   // bf16x2 table copy (~24.5 MB); sort arrays after

__device__ inline unsigned short f2bf(float f){
  unsigned u = __float_as_uint(f);
  u = (u + 0x7FFFu + ((u >> 16) & 1u)) >> 16;
  return (unsigned short)u;
}
__device__ inline float bf2f(unsigned short h){
  return __uint_as_float(((unsigned)h) << 16);
}
// fast softplus(beta=100): |err| < 1e-7 absolute, far below bf16 storage rounding
__device__ inline float softplus100_fast(float x){
  float y = 100.f * x;
  return 0.01f * (fmaxf(y, 0.f) + __logf(1.f + __expf(-fabsf(y))));
}
__device__ inline unsigned morton5(unsigned cx, unsigned cy, unsigned cz){
  unsigned k = 0;
  #pragma unroll
  for (int b = 0; b < 5; b++){
    k |= ((cx >> b) & 1u) << (3*b)
       | ((cy >> b) & 1u) << (3*b + 1)
       | ((cz >> b) & 1u) << (3*b + 2);
  }
  return k;
}

// ---- precompute 1: weight-norm row scales ----
__global__ void scale_kernel(const float* __restrict__ v0, const float* __restrict__ g0,
                             const float* __restrict__ v1, const float* __restrict__ g1,
                             const float* __restrict__ v2, const float* __restrict__ g2,
                             char* __restrict__ ws){
  int r = blockIdx.x * 256 + threadIdx.x;
  if (r < 256){
    float s = 0.f;
    for (int k = 0; k < 71; k++){ float t = v0[r*71+k]; s += t*t; }
    ((float*)(ws + S0_OFF))[r] = g0[r] / sqrtf(s);
  } else if (r < 512){
    int o = r - 256; float s = 0.f;
    for (int k = 0; k < 256; k++){ float t = v1[o*256+k]; s += t*t; }
    ((float*)(ws + S1_OFF))[o] = g1[o] / sqrtf(s);
  } else if (r < 769){
    int o = r - 512; float s = 0.f;
    for (int k = 0; k < 256; k++){ float t = v2[o*256+k]; s += t*t; }
    ((float*)(ws + S2_OFF))[o] = g2[o] / sqrtf(s);
  }
}

// ---- precompute 2: pack normalized weights into MFMA B-fragment order (bf16) ----
__global__ void pack_kernel(const float* __restrict__ v0, const float* __restrict__ v1,
                            const float* __restrict__ v2, char* __restrict__ ws){
  int i = blockIdx.x * 256 + threadIdx.x;
  const float* s0 = (const float*)(ws + S0_OFF);
  const float* s1 = (const float*)(ws + S1_OFF);
  const float* s2 = (const float*)(ws + S2_OFF);
  if (i < 24576){                  // B0: 16 nt * 3 kt * 512
    int j = i & 7, l = (i >> 3) & 63, q = i >> 9;
    int kt = q % 3, nt = q / 3;
    int k = kt*32 + (l >> 4)*8 + j, col = nt*16 + (l & 15);
    float v = (k < 71) ? v0[col*71 + k] * s0[col] : 0.f;
    ((unsigned short*)(ws + B0_OFF))[i] = f2bf(v);
  } else if (i < 90112){           // B1: 16 nt * 8 kt * 512
    int e = i - 24576;
    int j = e & 7, l = (e >> 3) & 63, q = e >> 9;
    int kt = q & 7, nt = q >> 3;
    int k = kt*32 + (l >> 4)*8 + j, col = nt*16 + (l & 15);
    ((unsigned short*)(ws + B1_OFF))[e] = f2bf(v1[col*256 + k] * s1[col]);
  } else if (i < 155648){          // B2 (first 256 out rows)
    int e = i - 90112;
    int j = e & 7, l = (e >> 3) & 63, q = e >> 9;
    int kt = q & 7, nt = q >> 3;
    int k = kt*32 + (l >> 4)*8 + j, col = nt*16 + (l & 15);
    ((unsigned short*)(ws + B2_OFF))[e] = f2bf(v2[col*256 + k] * s2[col]);
  } else if (i < 155904){          // w2 last row, fp32
    int k = i - 155648;
    ((float*)(ws + W2L_OFF))[k] = v2[256*256 + k] * s2[256];
  }
}

// ---- precompute 3: table f32 -> packed bf16x2 (one uint per entry) ----
__global__ void tconv_kernel(const float* __restrict__ table, char* __restrict__ ws, int total){
  int i = blockIdx.x * 256 + threadIdx.x;
  if (i < total){
    float2 v = ((const float2*)table)[i];
    unsigned lo = ((unsigned)f2bf(v.x));
    unsigned hi = ((unsigned)f2bf(v.y)) << 16;
    ((unsigned*)(ws + TBF_OFF))[i] = lo | hi;
  }
}

// ---- sort pass 1: cell key + histogram ----
__global__ void hist_kernel(const float* __restrict__ xin,
                            unsigned* __restrict__ hist, unsigned* __restrict__ keys){
  int i = blockIdx.x * 256 + threadIdx.x;
  float x0 = xin[i*3], x1 = xin[i*3+1], x2 = xin[i*3+2];
  unsigned cx = min(31u, (unsigned)(x0 * 32.f));
  unsigned cy = min(31u, (unsigned)(x1 * 32.f));
  unsigned cz = min(31u, (unsigned)(x2 * 32.f));
  unsigned k = morton5(cx, cy, cz);
  keys[i] = k;
  atomicAdd(&hist[k], 1u);
}

// ---- sort pass 2: exclusive scan of 32768 counters (single block) ----
__global__ __launch_bounds__(1024) void scan_kernel(unsigned* __restrict__ hist){
  __shared__ unsigned sdata[1024];
  int t = threadIdx.x;
  unsigned loc[32];
  unsigned s = 0;
  #pragma unroll
  for (int k = 0; k < 32; k++){ loc[k] = hist[t*32 + k]; s += loc[k]; }
  sdata[t] = s;
  __syncthreads();
  for (int d = 1; d < 1024; d <<= 1){
    unsigned v = (t >= d) ? sdata[t - d] : 0u;
    __syncthreads();
    sdata[t] += v;
    __syncthreads();
  }
  unsigned run = (t == 0) ? 0u : sdata[t - 1];
  #pragma unroll
  for (int k = 0; k < 32; k++){ unsigned c = loc[k]; hist[t*32 + k] = run; run += c; }
}

// ---- sort pass 3: scatter point ids into sorted order ----
__global__ void scatter_kernel(const unsigned* __restrict__ keys,
                               unsigned* __restrict__ hist, int* __restrict__ perm){
  int i = blockIdx.x * 256 + threadIdx.x;
  unsigned k = keys[i];
  unsigned r = atomicAdd(&hist[k], 1u);
  perm[r] = i;
}

// ============================================================================
// Fused v3: 64 (spatially sorted) points per block, 4 waves.
// Gather ILP (32 loads in flight) + MFMA MLP + direct scattered stores.
// ============================================================================
template<int USEBF>
__global__ __launch_bounds__(256, 4) void fused3(
    const float* __restrict__ xin, const float* __restrict__ table,
    char* __restrict__ ws, const int* __restrict__ perm,
    const float* __restrict__ b0, const float* __restrict__ b1, const float* __restrict__ b2,
    float* __restrict__ out, HashCfg cfg)
{
  __shared__ unsigned short buf[64 * 256];  // swizzled: elem(row,col) at col^((row&7)<<3)
  __shared__ float colsc[4][64];
  __shared__ int pids[64];

  const int tid = threadIdx.x;
  const int p   = tid & 63;        // local point / row
  const int grp = tid >> 6;        // wave id
  // XCD-contiguity swizzle: sorted-consecutive blocks land on the same XCD L2
  const int lb  = (blockIdx.x & 7) * 1024 + (blockIdx.x >> 3);
  const int idx = lb * 64 + p;
  const int pid = perm ? perm[idx] : idx;
  if (grp == 0) pids[p] = pid;

  const float x0 = xin[pid*3], x1 = xin[pid*3+1], x2 = xin[pid*3+2];
  const unsigned* __restrict__ tbf = (const unsigned*)(ws + TBF_OFF);

  auto stB = [&](int row, int col, float v){
    buf[row*256 + (col ^ ((row & 7) << 3))] = f2bf(v);
  };
  auto ldB = [&](int row, int kb) -> short8 {
    return *(const short8*)&buf[row*256 + (kb ^ ((row & 7) << 3))];
  };

  // ---------- phase E: features (issue all 32 gathers, then trig, then consume) ----------
  {
    float wxa[4], wya[4], wza[4];
    unsigned vb[4][8];
    float2   vf2[4][8];

    #pragma unroll
    for (int ii = 0; ii < 4; ii++){
      int lev = grp*4 + ii;
      int res = cfg.res[lev];
      float scl = (float)(res - 1);
      float px = x0*scl, py = x1*scl, pz = x2*scl;
      float fx = floorf(px), fy = floorf(py), fz = floorf(pz);
      wxa[ii] = px - fx; wya[ii] = py - fy; wza[ii] = pz - fz;
      unsigned cx0 = (unsigned)fx, cy0 = (unsigned)fy, cz0 = (unsigned)fz;
      unsigned r1 = (unsigned)(res + 1);
      bool hl = (cfg.hashed_mask >> lev) & 1;
      unsigned base = (unsigned)cfg.off[lev];
      #pragma unroll
      for (int c = 0; c < 8; c++){
        unsigned bx = (c >> 2) & 1, by = (c >> 1) & 1, bz = c & 1;
        unsigned cx = cx0 + bx, cy = cy0 + by, cz = cz0 + bz;
        unsigned hidx = hl ? ((cx ^ (cy * 2654435761u) ^ (cz * 805459861u)) & TMASK)
                           : (cx + cy * r1 + cz * r1 * r1);
        if (USEBF) vb[ii][c]  = tbf[base + hidx];
        else       vf2[ii][c] = *(const float2*)(table + (size_t)(base + hidx) * 2u);
      }
    }

    // trig / input / K-pad overlaps gather latency
    if (grp < 3){
      float xv[3] = {x0, x1, x2};
      #pragma unroll
      for (int fi = 0; fi < 2; fi++){
        int f = grp*2 + fi;
        float fr = (float)(1 << f);
        #pragma unroll
        for (int d = 0; d < 3; d++){
          float a = xv[d] * fr;
          stB(p, 3 + f*6 + d,     __sinf(a));
          stB(p, 3 + f*6 + 3 + d, __cosf(a));
        }
      }
    } else {
      stB(p, 0, x0); stB(p, 1, x1); stB(p, 2, x2);
      #pragma unroll
      for (int c = 71; c < 96; c++)
        buf[p*256 + (c ^ ((p & 7) << 3))] = 0;
    }

    #pragma unroll
    for (int ii = 0; ii < 4; ii++){
      int lev = grp*4 + ii;
      float wx = wxa[ii], wy = wya[ii], wz = wza[ii];
      float f0 = 0.f, f1 = 0.f;
      #pragma unroll
      for (int c = 0; c < 8; c++){
        unsigned bx = (c >> 2) & 1, by = (c >> 1) & 1, bz = c & 1;
        float w = (bx ? wx : 1.f - wx) * (by ? wy : 1.f - wy) * (bz ? wz : 1.f - wz);
        if (USEBF){
          unsigned u = vb[ii][c];
          f0 += w * __uint_as_float(u << 16);
          f1 += w * __uint_as_float(u & 0xffff0000u);
        } else {
          f0 += w * vf2[ii][c].x;
          f1 += w * vf2[ii][c].y;
        }
      }
      stB(p, 39 + 2*lev, f0);
      stB(p, 40 + 2*lev, f1);
    }
  }
  __syncthreads();

  // ---------- MFMA phases ----------
  const int l  = tid & 63;
  const int lr = l & 15;    // A-row / C-col within tile
  const int lh = l >> 4;    // k-group; C-row = lh*4 + j
  const int wv = grp;       // wave owns output cols [wv*64, wv*64+64)
  const short8* B0p = (const short8*)(ws + B0_OFF);
  const short8* B1p = (const short8*)(ws + B1_OFF);
  const short8* B2p = (const short8*)(ws + B2_OFF);

  { // ----- layer 0 -----
    f32x4 acc[4][4];
    #pragma unroll
    for (int a = 0; a < 4; a++)
      #pragma unroll
      for (int b = 0; b < 4; b++) acc[a][b] = (f32x4){0.f,0.f,0.f,0.f};
    #pragma unroll
    for (int kt = 0; kt < 3; kt++){
      short8 af[4];
      #pragma unroll
      for (int mt = 0; mt < 4; mt++) af[mt] = ldB(mt*16 + lr, kt*32 + lh*8);
      #pragma unroll
      for (int nt = 0; nt < 4; nt++){
        short8 bf = B0p[((wv*4 + nt)*3 + kt)*64 + l];
        #pragma unroll
        for (int mt = 0; mt < 4; mt++)
          acc[mt][nt] = __builtin_amdgcn_mfma_f32_16x16x32_bf16(af[mt], bf, acc[mt][nt], 0, 0, 0);
      }
    }
    __syncthreads();   // all feature reads complete before h1 overwrites buf
    float bb[4];
    #pragma unroll
    for (int nt = 0; nt < 4; nt++) bb[nt] = b0[wv*64 + nt*16 + lr];
    #pragma unroll
    for (int mt = 0; mt < 4; mt++)
      #pragma unroll
      for (int nt = 0; nt < 4; nt++){
        int c = wv*64 + nt*16 + lr;
        #pragma unroll
        for (int j = 0; j < 4; j++)
          stB(mt*16 + lh*4 + j, c, softplus100_fast(acc[mt][nt][j] + bb[nt]));
      }
  }
  __syncthreads();

  { // ----- layer 1 -----
    f32x4 acc[4][4];
    #pragma unroll
    for (int a = 0; a < 4; a++)
      #pragma unroll
      for (int b = 0; b < 4; b++) acc[a][b] = (f32x4){0.f,0.f,0.f,0.f};
    #pragma unroll
    for (int kt = 0; kt < 8; kt++){
      short8 af[4];
      #pragma unroll
      for (int mt = 0; mt < 4; mt++) af[mt] = ldB(mt*16 + lr, kt*32 + lh*8);
      #pragma unroll
      for (int nt = 0; nt < 4; nt++){
        short8 bf = B1p[((wv*4 + nt)*8 + kt)*64 + l];
        #pragma unroll
        for (int mt = 0; mt < 4; mt++)
          acc[mt][nt] = __builtin_amdgcn_mfma_f32_16x16x32_bf16(af[mt], bf, acc[mt][nt], 0, 0, 0);
      }
    }
    __syncthreads();   // all h1 reads complete before h2 overwrites buf
    float bb[4];
    #pragma unroll
    for (int nt = 0; nt < 4; nt++) bb[nt] = b1[wv*64 + nt*16 + lr];
    #pragma unroll
    for (int mt = 0; mt < 4; mt++)
      #pragma unroll
      for (int nt = 0; nt < 4; nt++){
        int c = wv*64 + nt*16 + lr;
        #pragma unroll
        for (int j = 0; j < 4; j++)
          stB(mt*16 + lh*4 + j, c, softplus100_fast(acc[mt][nt][j] + bb[nt]));
      }
  }
  __syncthreads();  // h2 visible to all

  // last-col partials: thread (wv,l) handles row l, cols [wv*64, wv*64+64)
  {
    const float* w2l = (const float*)(ws + W2L_OFF);
    float s = 0.f;
    #pragma unroll
    for (int q = 0; q < 8; q++){
      short8 h = ldB(l, wv*64 + q*8);
      #pragma unroll
      for (int j = 0; j < 8; j++)
        s += bf2f((unsigned short)h[j]) * w2l[wv*64 + q*8 + j];
    }
    colsc[wv][l] = s;
  }

  { // ----- layer 2 + direct scattered stores -----
    f32x4 acc[4][4];
    #pragma unroll
    for (int a = 0; a < 4; a++)
      #pragma unroll
      for (int b = 0; b < 4; b++) acc[a][b] = (f32x4){0.f,0.f,0.f,0.f};
    #pragma unroll
    for (int kt = 0; kt < 8; kt++){
      short8 af[4];
      #pragma unroll
      for (int mt = 0; mt < 4; mt++) af[mt] = ldB(mt*16 + lr, kt*32 + lh*8);
      #pragma unroll
      for (int nt = 0; nt < 4; nt++){
        short8 bf = B2p[((wv*4 + nt)*8 + kt)*64 + l];
        #pragma unroll
        for (int mt = 0; mt < 4; mt++)
          acc[mt][nt] = __builtin_amdgcn_mfma_f32_16x16x32_bf16(af[mt], bf, acc[mt][nt], 0, 0, 0);
      }
    }
    __syncthreads();   // colsc partials visible
    float bb[4];
    #pragma unroll
    for (int nt = 0; nt < 4; nt++) bb[nt] = b2[wv*64 + nt*16 + lr];
    int rowid[4][4];
    #pragma unroll
    for (int mt = 0; mt < 4; mt++)
      #pragma unroll
      for (int j = 0; j < 4; j++) rowid[mt][j] = pids[mt*16 + lh*4 + j];
    #pragma unroll
    for (int mt = 0; mt < 4; mt++)
      #pragma unroll
      for (int nt = 0; nt < 4; nt++){
        int c = wv*64 + nt*16 + lr;
        #pragma unroll
        for (int j = 0; j < 4; j++)
          out[(size_t)rowid[mt][j]*257 + c] = acc[mt][nt][j] + bb[nt];
      }
    if (tid < 64)
      out[(size_t)pids[tid]*257 + 256] =
        colsc[0][tid] + colsc[1][tid] + colsc[2][tid] + colsc[3][tid] + b2[256];
  }
}

// ---- host: replicate reference's double-precision level config exactly ----
static HashCfg make_cfg(){
  HashCfg c;
  double pls = exp2(log2(2048.0 / 16.0) / 15.0);
  long long off = 0;
  unsigned mask = 0;
  for (int l = 0; l < 16; l++){
    int r = (int)ceil(16.0 * pow(pls, (double)l));
    c.res[l] = r;
    c.off[l] = (int)off;
    double n3 = (double)(r + 1) * (double)(r + 1) * (double)(r + 1);
    long long size;
    if (n3 > 524288.0){ mask |= (1u << l); }
    size = (long long)(ceil(n3 / 8.0) * 8.0);
    if (size > 524288) size = 524288;
    off += size;
  }
  c.hashed_mask = mask;
  c.total = (int)off;
  return c;
}

extern "C" void kernel_launch(void* const* d_in, const int* in_sizes, int n_in,
                              void* d_out, int out_size, void* d_ws, size_t ws_size,
                              hipStream_t stream) {
  const float* x     = (const float*)d_in[0];
  const float* table = (const float*)d_in[1];
  const float* v0 = (const float*)d_in[2];
  const float* g0 = (const float*)d_in[3];
  const float* b0 = (const float*)d_in[4];
  const float* v1 = (const float*)d_in[5];
  const float* g1 = (const float*)d_in[6];
  const float* b1 = (const float*)d_in[7];
  const float* v2 = (const float*)d_in[8];
  const float* g2 = (const float*)d_in[9];
  const float* b2 = (const float*)d_in[10];
  float* out = (float*)d_out;
  char* ws = (char*)d_ws;

  HashCfg cfg = make_cfg();
  size_t tbf_bytes = (size_t)cfg.total * 4u;
  size_t hist_off  = (TBF_OFF + tbf_bytes + 255) & ~(size_t)255;
  size_t keys_off  = hist_off + (size_t)NCELLS * 4;
  size_t perm_off  = keys_off + (size_t)N_POINTS * 4;
  size_t need_sort = perm_off + (size_t)N_POINTS * 4;
  size_t need_bf   = TBF_OFF + tbf_bytes;

  hipLaunchKernelGGL(scale_kernel, dim3(4), dim3(256), 0, stream, v0, g0, v1, g1, v2, g2, ws);
  hipLaunchKernelGGL(pack_kernel, dim3(609), dim3(256), 0, stream, v0, v1, v2, ws);

  if (ws_size >= need_sort){
    unsigned* hist = (unsigned*)(ws + hist_off);
    unsigned* keys = (unsigned*)(ws + keys_off);
    int*      perm = (int*)(ws + perm_off);
    hipMemsetAsync(hist, 0, (size_t)NCELLS * 4, stream);
    hipLaunchKernelGGL(tconv_kernel, dim3((cfg.total + 255) / 256), dim3(256), 0, stream,
                       table, ws, cfg.total);
    hipLaunchKernelGGL(hist_kernel, dim3(N_POINTS / 256), dim3(256), 0, stream, x, hist, keys);
    hipLaunchKernelGGL(scan_kernel, dim3(1), dim3(1024), 0, stream, hist);
    hipLaunchKernelGGL(scatter_kernel, dim3(N_POINTS / 256), dim3(256), 0, stream, keys, hist, perm);
    hipLaunchKernelGGL((fused3<1>), dim3(N_POINTS / 64), dim3(256), 0, stream,
                       x, table, ws, perm, b0, b1, b2, out, cfg);
  } else if (ws_size >= need_bf){
    hipLaunchKernelGGL(tconv_kernel, dim3((cfg.total + 255) / 256), dim3(256), 0, stream,
                       table, ws, cfg.total);
    hipLaunchKernelGGL((fused3<1>), dim3(N_POINTS / 64), dim3(256), 0, stream,
                       x, table, ws, (const int*)nullptr, b0, b1, b2, out, cfg);
  } else {
    hipLaunchKernelGGL((fused3<0>), dim3(N_POINTS / 64), dim3(256), 0, stream,
                       x, table, ws, (const int*)nullptr, b0, b1, b2, out, cfg);
  }
}